// Round 1
// baseline (1175.617 us; speedup 1.0000x reference)
//
#include <hip/hip_runtime.h>
#include <math.h>

// Shapes: B=8, N_L=256, C=256, NH=8, HD=32, H=W=64, N_C=4096, L=3, KS={3,5,7}
// SCALE = 1/sqrt(32)

namespace {

constexpr float CSCALE = 0.17677669529663688f;

__device__ __forceinline__ float gelu_f(float x) {
  return 0.5f * x * (1.0f + erff(x * 0.70710678118654752f));
}

// ---------------------------------------------------------------------------
// Generic GEMM: out[r][n] = sum_k X[r][k] * W[n][k] + bias[n]   (K = 256)
// rows = grid.x*64 (exact), N = grid.y*64 (exact)
// ---------------------------------------------------------------------------
__global__ __launch_bounds__(256) void gemm_xwt(
    const float* __restrict__ X, const float* __restrict__ W,
    const float* __restrict__ bias, float* __restrict__ out, int N) {
  __shared__ float As[64][33];
  __shared__ float Bs[64][33];
  const int tid = threadIdx.x;
  const int r0 = blockIdx.x * 64, n0 = blockIdx.y * 64;
  const int row = tid & 63, kq = (tid >> 6) * 8;
  const int ty = tid >> 4, tx = tid & 15;
  float acc[4][4] = {};
  for (int k0 = 0; k0 < 256; k0 += 32) {
    const float4* xp = (const float4*)(X + (size_t)(r0 + row) * 256 + k0 + kq);
    float4 a0 = xp[0], a1 = xp[1];
    const float4* wp = (const float4*)(W + (size_t)(n0 + row) * 256 + k0 + kq);
    float4 b0 = wp[0], b1 = wp[1];
    As[row][kq+0]=a0.x; As[row][kq+1]=a0.y; As[row][kq+2]=a0.z; As[row][kq+3]=a0.w;
    As[row][kq+4]=a1.x; As[row][kq+5]=a1.y; As[row][kq+6]=a1.z; As[row][kq+7]=a1.w;
    Bs[row][kq+0]=b0.x; Bs[row][kq+1]=b0.y; Bs[row][kq+2]=b0.z; Bs[row][kq+3]=b0.w;
    Bs[row][kq+4]=b1.x; Bs[row][kq+5]=b1.y; Bs[row][kq+6]=b1.z; Bs[row][kq+7]=b1.w;
    __syncthreads();
    #pragma unroll
    for (int k = 0; k < 32; ++k) {
      float a[4], bv[4];
      #pragma unroll
      for (int i = 0; i < 4; ++i) a[i] = As[ty*4+i][k];
      #pragma unroll
      for (int j = 0; j < 4; ++j) bv[j] = Bs[tx*4+j][k];
      #pragma unroll
      for (int i = 0; i < 4; ++i)
        #pragma unroll
        for (int j = 0; j < 4; ++j) acc[i][j] += a[i] * bv[j];
    }
    __syncthreads();
  }
  #pragma unroll
  for (int j = 0; j < 4; ++j) {
    const int n = n0 + tx*4 + j;
    const float bb = bias ? bias[n] : 0.0f;
    #pragma unroll
    for (int i = 0; i < 4; ++i)
      out[(size_t)(r0 + ty*4 + i) * N + n] = acc[i][j] + bb;
  }
}

// ---------------------------------------------------------------------------
// f-projection: f_out[r][n] = context[r][:] . f_w[n][:] + f_b[n], n in [0,260)
// scatter: n<256 -> vctx[b][n][hw] (planar), n>=256 -> gates[b][n-256][hw]
// r = b*4096 + hw.  grid = (512, 5)
// ---------------------------------------------------------------------------
__global__ __launch_bounds__(256) void gemm_f(
    const float* __restrict__ ctx, const float* __restrict__ fw,
    const float* __restrict__ fb, float* __restrict__ vctx,
    float* __restrict__ gates) {
  __shared__ float As[64][33];
  __shared__ float Bs[64][33];
  const int tid = threadIdx.x;
  const int r0 = blockIdx.x * 64, n0 = blockIdx.y * 64;
  const int row = tid & 63, kq = (tid >> 6) * 8;
  const int ty = tid >> 4, tx = tid & 15;
  float acc[4][4] = {};
  for (int k0 = 0; k0 < 256; k0 += 32) {
    const float4* xp = (const float4*)(ctx + (size_t)(r0 + row) * 256 + k0 + kq);
    float4 a0 = xp[0], a1 = xp[1];
    float4 b0 = make_float4(0.f,0.f,0.f,0.f), b1 = b0;
    if (n0 + row < 260) {
      const float4* wp = (const float4*)(fw + (size_t)(n0 + row) * 256 + k0 + kq);
      b0 = wp[0]; b1 = wp[1];
    }
    As[row][kq+0]=a0.x; As[row][kq+1]=a0.y; As[row][kq+2]=a0.z; As[row][kq+3]=a0.w;
    As[row][kq+4]=a1.x; As[row][kq+5]=a1.y; As[row][kq+6]=a1.z; As[row][kq+7]=a1.w;
    Bs[row][kq+0]=b0.x; Bs[row][kq+1]=b0.y; Bs[row][kq+2]=b0.z; Bs[row][kq+3]=b0.w;
    Bs[row][kq+4]=b1.x; Bs[row][kq+5]=b1.y; Bs[row][kq+6]=b1.z; Bs[row][kq+7]=b1.w;
    __syncthreads();
    #pragma unroll
    for (int k = 0; k < 32; ++k) {
      float a[4], bv[4];
      #pragma unroll
      for (int i = 0; i < 4; ++i) a[i] = As[ty*4+i][k];
      #pragma unroll
      for (int j = 0; j < 4; ++j) bv[j] = Bs[tx*4+j][k];
      #pragma unroll
      for (int i = 0; i < 4; ++i)
        #pragma unroll
        for (int j = 0; j < 4; ++j) acc[i][j] += a[i] * bv[j];
    }
    __syncthreads();
  }
  #pragma unroll
  for (int j = 0; j < 4; ++j) {
    const int n = n0 + tx*4 + j;
    if (n >= 260) continue;
    const float bb = fb[n];
    #pragma unroll
    for (int i = 0; i < 4; ++i) {
      const int r = r0 + ty*4 + i;
      const int b = r >> 12, hw = r & 4095;
      const float v = acc[i][j] + bb;
      if (n < 256) vctx[((size_t)(b*256 + n)) * 4096 + hw] = v;
      else         gates[((size_t)(b*4 + (n - 256))) * 4096 + hw] = v;
    }
  }
}

// ---------------------------------------------------------------------------
// Depthwise conv + GELU, one (b,c) 64x64 plane per block. grid = 2048
// ---------------------------------------------------------------------------
template<int KK, int LYR, bool FIRST>
__global__ __launch_bounds__(256) void dwconv(
    const float* __restrict__ in, const float* __restrict__ wk,
    const float* __restrict__ gates, float* __restrict__ outv,
    float* __restrict__ vall) {
  constexpr int P = KK / 2, TW = 64 + 2 * P;
  __shared__ float tile[TW * TW];
  __shared__ float wsh[KK * KK];
  const int tid = threadIdx.x;
  const int b = blockIdx.x >> 8, c = blockIdx.x & 255;
  const float* ip = in + (size_t)(b*256 + c) * 4096;
  if (tid < KK*KK) wsh[tid] = wk[c*KK*KK + tid];
  for (int idx = tid; idx < TW*TW; idx += 256) {
    const int ty = idx / TW, tx = idx - ty*TW;
    const int gy = ty - P, gx = tx - P;
    tile[idx] = (gy >= 0 && gy < 64 && gx >= 0 && gx < 64) ? ip[gy*64 + gx] : 0.0f;
  }
  __syncthreads();
  const float* gl = gates + (size_t)(b*4 + LYR) * 4096;
  float* vp = vall + (size_t)(b*256 + c) * 4096;
  float* op = outv + (size_t)(b*256 + c) * 4096;
  #pragma unroll
  for (int ii = 0; ii < 16; ++ii) {
    const int pix = ii*256 + tid;
    const int y = pix >> 6, x = pix & 63;
    float acc = 0.f;
    #pragma unroll
    for (int ky = 0; ky < KK; ++ky)
      #pragma unroll
      for (int kx = 0; kx < KK; ++kx)
        acc += wsh[ky*KK + kx] * tile[(y+ky)*TW + (x+kx)];
    const float g = gelu_f(acc);
    op[pix] = g;
    const float t = g * gl[pix];
    if (FIRST) vp[pix] = t; else vp[pix] += t;
  }
}

// Last conv (k=7, layer 2) + global-mean term, no v_ctx output needed.
__global__ __launch_bounds__(256) void dwconv7(
    const float* __restrict__ in, const float* __restrict__ wk,
    const float* __restrict__ gates, float* __restrict__ vall) {
  constexpr int KK = 7, P = 3, TW = 70;
  __shared__ float tile[TW * TW];
  __shared__ float wsh[KK * KK];
  __shared__ float red[4];
  const int tid = threadIdx.x;
  const int b = blockIdx.x >> 8, c = blockIdx.x & 255;
  const float* ip = in + (size_t)(b*256 + c) * 4096;
  if (tid < KK*KK) wsh[tid] = wk[c*KK*KK + tid];
  for (int idx = tid; idx < TW*TW; idx += 256) {
    const int ty = idx / TW, tx = idx - ty*TW;
    const int gy = ty - P, gx = tx - P;
    tile[idx] = (gy >= 0 && gy < 64 && gx >= 0 && gx < 64) ? ip[gy*64 + gx] : 0.0f;
  }
  __syncthreads();
  float gv[16];
  #pragma unroll
  for (int ii = 0; ii < 16; ++ii) {
    const int pix = ii*256 + tid;
    const int y = pix >> 6, x = pix & 63;
    float acc = 0.f;
    #pragma unroll
    for (int ky = 0; ky < KK; ++ky)
      #pragma unroll
      for (int kx = 0; kx < KK; ++kx)
        acc += wsh[ky*KK + kx] * tile[(y+ky)*TW + (x+kx)];
    gv[ii] = gelu_f(acc);
  }
  float s = 0.f;
  #pragma unroll
  for (int ii = 0; ii < 16; ++ii) s += gv[ii];
  #pragma unroll
  for (int off = 32; off >= 1; off >>= 1) s += __shfl_xor(s, off, 64);
  if ((tid & 63) == 0) red[tid >> 6] = s;
  __syncthreads();
  const float vg = gelu_f((red[0]+red[1]+red[2]+red[3]) * (1.0f/4096.0f));
  const float* g2 = gates + (size_t)(b*4 + 2) * 4096;
  const float* g3 = gates + (size_t)(b*4 + 3) * 4096;
  float* vp = vall + (size_t)(b*256 + c) * 4096;
  #pragma unroll
  for (int ii = 0; ii < 16; ++ii) {
    const int pix = ii*256 + tid;
    vp[pix] += gv[ii]*g2[pix] + vg*g3[pix];
  }
}

// ---------------------------------------------------------------------------
// h-GEMM over channels: v_mod[b,d,hw] = sum_c h_w[d,c]*v_all[b,c,hw] + h_b[d]
// written permuted: vlin[b][m = d*16 + hw/256][col = hw%256]
// grid = (64 hw-tiles, 4 d-tiles, 8 b)
// ---------------------------------------------------------------------------
__global__ __launch_bounds__(256) void gemm_h(
    const float* __restrict__ vall, const float* __restrict__ hwm,
    const float* __restrict__ hb, float* __restrict__ vlin) {
  __shared__ float As[32][65];   // [c][hw]
  __shared__ float Bs[64][33];   // [d][c]
  const int tid = threadIdx.x;
  const int hw0 = blockIdx.x * 64, d0 = blockIdx.y * 64, b = blockIdx.z;
  const int ty = tid >> 4, tx = tid & 15;
  float acc[4][4] = {};
  for (int c0 = 0; c0 < 256; c0 += 32) {
    const int cc = tid >> 3, hwi = (tid & 7) * 8;
    const float4* vp = (const float4*)(vall + (size_t)(b*256 + c0 + cc)*4096 + hw0 + hwi);
    float4 a0 = vp[0], a1 = vp[1];
    As[cc][hwi+0]=a0.x; As[cc][hwi+1]=a0.y; As[cc][hwi+2]=a0.z; As[cc][hwi+3]=a0.w;
    As[cc][hwi+4]=a1.x; As[cc][hwi+5]=a1.y; As[cc][hwi+6]=a1.z; As[cc][hwi+7]=a1.w;
    const int dd = tid & 63, cq = (tid >> 6) * 8;
    const float4* wp = (const float4*)(hwm + (size_t)(d0 + dd)*256 + c0 + cq);
    float4 b0 = wp[0], b1 = wp[1];
    Bs[dd][cq+0]=b0.x; Bs[dd][cq+1]=b0.y; Bs[dd][cq+2]=b0.z; Bs[dd][cq+3]=b0.w;
    Bs[dd][cq+4]=b1.x; Bs[dd][cq+5]=b1.y; Bs[dd][cq+6]=b1.z; Bs[dd][cq+7]=b1.w;
    __syncthreads();
    #pragma unroll
    for (int k = 0; k < 32; ++k) {
      float a[4], bv[4];
      #pragma unroll
      for (int i = 0; i < 4; ++i) a[i] = As[k][ty*4+i];
      #pragma unroll
      for (int j = 0; j < 4; ++j) bv[j] = Bs[tx*4+j][k];
      #pragma unroll
      for (int i = 0; i < 4; ++i)
        #pragma unroll
        for (int j = 0; j < 4; ++j) acc[i][j] += a[i] * bv[j];
    }
    __syncthreads();
  }
  #pragma unroll
  for (int j = 0; j < 4; ++j) {
    const int d = d0 + tx*4 + j;
    const float bb = hb[d];
    #pragma unroll
    for (int i = 0; i < 4; ++i) {
      const int hw = hw0 + ty*4 + i;
      const int m = d*16 + (hw >> 8);
      vlin[((size_t)b*4096 + m)*256 + (hw & 255)] = acc[i][j] + bb;
    }
  }
}

// ---------------------------------------------------------------------------
// Attention: one block = 4 q-rows of one (b,h). Single QK pass; logits tiny
// (|logit| < ~1) so no max-subtraction needed; write normalized attn.
// grid = 4096
// ---------------------------------------------------------------------------
__global__ __launch_bounds__(256) void attn_softmax(
    const float* __restrict__ q, const float* __restrict__ k,
    float* __restrict__ attn) {
  const int blk = blockIdx.x;
  const int b = blk >> 9, h = (blk >> 6) & 7, nt = blk & 63;
  const int n0 = nt * 4;
  const int tid = threadIdx.x;
  __shared__ float qs[4][32];
  __shared__ float red[4][4];
  if (tid < 128) {
    const int r = tid >> 5, d = tid & 31;
    qs[r][d] = q[(size_t)(b*256 + n0 + r)*256 + h*32 + d];
  }
  __syncthreads();
  const float* kb = k + (size_t)b*4096*256 + h*32;
  float e[4][16];
  #pragma unroll
  for (int i = 0; i < 16; ++i) {
    const int m = i*256 + tid;
    const float4* kp = (const float4*)(kb + (size_t)m*256);
    float4 kv[8];
    #pragma unroll
    for (int d4 = 0; d4 < 8; ++d4) kv[d4] = kp[d4];
    #pragma unroll
    for (int r = 0; r < 4; ++r) {
      float acc = 0.f;
      #pragma unroll
      for (int d4 = 0; d4 < 8; ++d4) {
        acc += kv[d4].x * qs[r][d4*4+0];
        acc += kv[d4].y * qs[r][d4*4+1];
        acc += kv[d4].z * qs[r][d4*4+2];
        acc += kv[d4].w * qs[r][d4*4+3];
      }
      e[r][i] = expf(acc * CSCALE);
    }
  }
  float s[4];
  #pragma unroll
  for (int r = 0; r < 4; ++r) {
    float t = 0.f;
    #pragma unroll
    for (int i = 0; i < 16; ++i) t += e[r][i];
    #pragma unroll
    for (int off = 32; off >= 1; off >>= 1) t += __shfl_xor(t, off, 64);
    s[r] = t;
  }
  if ((tid & 63) == 0) {
    const int w = tid >> 6;
    #pragma unroll
    for (int r = 0; r < 4; ++r) red[r][w] = s[r];
  }
  __syncthreads();
  float invS[4];
  #pragma unroll
  for (int r = 0; r < 4; ++r)
    invS[r] = 1.0f / (red[r][0] + red[r][1] + red[r][2] + red[r][3]);
  float* ab = attn + (size_t)((b*8 + h)*256 + n0) * 4096;
  #pragma unroll
  for (int r = 0; r < 4; ++r)
    #pragma unroll
    for (int i = 0; i < 16; ++i)
      ab[(size_t)r*4096 + i*256 + tid] = e[r][i] * invS[r];
}

// ---------------------------------------------------------------------------
// PV: out[b,h,n,d] = sum_m attn[b,h,n,m] * vlin[b,m,h*32+d]
// grid = (4 n-tiles, 64 bh); writes attn_out[b][n][h*32+d]
// ---------------------------------------------------------------------------
__global__ __launch_bounds__(256) void pv_gemm(
    const float* __restrict__ attn, const float* __restrict__ vlin,
    float* __restrict__ outs) {
  __shared__ float As[64][65];  // n x m-chunk
  __shared__ float Bs[64][33];  // m x d
  const int tid = threadIdx.x;
  const int n0 = blockIdx.x * 64;
  const int bh = blockIdx.y, b = bh >> 3, h = bh & 7;
  const int ty = tid >> 4, tx = tid & 15;
  float acc[4][2] = {};
  const float* ab = attn + ((size_t)bh*256 + n0) * 4096;
  const float* vb = vlin + (size_t)b*4096*256 + h*32;
  for (int m0 = 0; m0 < 4096; m0 += 64) {
    const int rr = tid >> 2, mi = (tid & 3) * 16;
    const float4* ap = (const float4*)(ab + (size_t)rr*4096 + m0 + mi);
    float4 a0 = ap[0], a1 = ap[1], a2 = ap[2], a3 = ap[3];
    As[rr][mi+ 0]=a0.x; As[rr][mi+ 1]=a0.y; As[rr][mi+ 2]=a0.z; As[rr][mi+ 3]=a0.w;
    As[rr][mi+ 4]=a1.x; As[rr][mi+ 5]=a1.y; As[rr][mi+ 6]=a1.z; As[rr][mi+ 7]=a1.w;
    As[rr][mi+ 8]=a2.x; As[rr][mi+ 9]=a2.y; As[rr][mi+10]=a2.z; As[rr][mi+11]=a2.w;
    As[rr][mi+12]=a3.x; As[rr][mi+13]=a3.y; As[rr][mi+14]=a3.z; As[rr][mi+15]=a3.w;
    const int mm = tid & 63, dq = (tid >> 6) * 8;
    const float4* vp = (const float4*)(vb + (size_t)(m0 + mm)*256 + dq);
    float4 b0 = vp[0], b1 = vp[1];
    Bs[mm][dq+0]=b0.x; Bs[mm][dq+1]=b0.y; Bs[mm][dq+2]=b0.z; Bs[mm][dq+3]=b0.w;
    Bs[mm][dq+4]=b1.x; Bs[mm][dq+5]=b1.y; Bs[mm][dq+6]=b1.z; Bs[mm][dq+7]=b1.w;
    __syncthreads();
    #pragma unroll
    for (int kk = 0; kk < 64; ++kk) {
      float a[4];
      #pragma unroll
      for (int i = 0; i < 4; ++i) a[i] = As[ty*4+i][kk];
      const float v0 = Bs[kk][tx*2+0], v1 = Bs[kk][tx*2+1];
      #pragma unroll
      for (int i = 0; i < 4; ++i) { acc[i][0] += a[i]*v0; acc[i][1] += a[i]*v1; }
    }
    __syncthreads();
  }
  #pragma unroll
  for (int i = 0; i < 4; ++i)
    #pragma unroll
    for (int j = 0; j < 2; ++j)
      outs[(size_t)(b*256 + n0 + ty*4 + i)*256 + h*32 + tx*2 + j] = acc[i][j];
}

} // namespace

extern "C" void kernel_launch(void* const* d_in, const int* in_sizes, int n_in,
                              void* d_out, int out_size, void* d_ws, size_t ws_size,
                              hipStream_t stream) {
  (void)in_sizes; (void)n_in; (void)out_size; (void)ws_size;
  const float* latents = (const float*)d_in[0];
  const float* context = (const float*)d_in[1];
  const float* q_w    = (const float*)d_in[2];
  const float* k_w    = (const float*)d_in[3];
  const float* f_w    = (const float*)d_in[4];
  const float* f_b    = (const float*)d_in[5];
  const float* h_w    = (const float*)d_in[6];
  const float* h_b    = (const float*)d_in[7];
  const float* fk0    = (const float*)d_in[8];
  const float* fk1    = (const float*)d_in[9];
  const float* fk2    = (const float*)d_in[10];
  const float* proj_w = (const float*)d_in[11];
  const float* proj_b = (const float*)d_in[12];

  float* out0 = (float*)d_out;                  // (8,256,256)
  float* attn = out0 + (size_t)8*256*256;       // (8,8,256,4096)

  // workspace layout (floats); total = 34,734,080 floats = ~139 MB
  float* w    = (float*)d_ws;
  float* qb    = w;                       // 524288
  float* kb    = qb   + 524288;           // 8388608
  float* buf1  = kb   + 8388608;          // 8388608  (f out -> conv3 in; conv5 out; conv7 in)
  float* buf2  = buf1 + 8388608;          // 8388608  (conv3 out -> conv5 in; later vlin)
  float* gates = buf2 + 8388608;          // 131072
  float* vall  = gates + 131072;          // 8388608
  float* aout  = vall + 8388608;          // 524288
  float* vlin  = buf2;                    // alias: buf2 dead after conv5

  gemm_xwt<<<dim3(32, 4),  256, 0, stream>>>(latents, q_w, nullptr, qb, 256);
  gemm_xwt<<<dim3(512, 4), 256, 0, stream>>>(context, k_w, nullptr, kb, 256);
  gemm_f  <<<dim3(512, 5), 256, 0, stream>>>(context, f_w, f_b, buf1, gates);
  dwconv<3, 0, true ><<<2048, 256, 0, stream>>>(buf1, fk0, gates, buf2, vall);
  dwconv<5, 1, false><<<2048, 256, 0, stream>>>(buf2, fk1, gates, buf1, vall);
  dwconv7            <<<2048, 256, 0, stream>>>(buf1, fk2, gates, vall);
  gemm_h  <<<dim3(64, 4, 8), 256, 0, stream>>>(vall, h_w, h_b, vlin);
  attn_softmax<<<4096, 256, 0, stream>>>(qb, kb, attn);
  pv_gemm <<<dim3(4, 64), 256, 0, stream>>>(attn, vlin, aout);
  gemm_xwt<<<dim3(32, 4), 256, 0, stream>>>(aout, proj_w, proj_b, out0, 256);
}

// Round 2
// 738.271 us; speedup vs baseline: 1.5924x; 1.5924x over previous
//
#include <hip/hip_runtime.h>
#include <math.h>

// Shapes: B=8, N_L=256, C=256, NH=8, HD=32, H=W=64, N_C=4096, L=3, KS={3,5,7}
// SCALE = 1/sqrt(32)

namespace {

constexpr float CSCALE = 0.17677669529663688f;

__device__ __forceinline__ float gelu_f(float x) {
  return 0.5f * x * (1.0f + erff(x * 0.70710678118654752f));
}

// ---------------------------------------------------------------------------
// Generic GEMM: out[r][n] = sum_k X[r][k] * W[n][k] + bias[n]   (K = 256)
// ---------------------------------------------------------------------------
__global__ __launch_bounds__(256) void gemm_xwt(
    const float* __restrict__ X, const float* __restrict__ W,
    const float* __restrict__ bias, float* __restrict__ out, int N) {
  __shared__ float As[64][33];
  __shared__ float Bs[64][33];
  const int tid = threadIdx.x;
  const int r0 = blockIdx.x * 64, n0 = blockIdx.y * 64;
  const int row = tid & 63, kq = (tid >> 6) * 8;
  const int ty = tid >> 4, tx = tid & 15;
  float acc[4][4] = {};
  for (int k0 = 0; k0 < 256; k0 += 32) {
    const float4* xp = (const float4*)(X + (size_t)(r0 + row) * 256 + k0 + kq);
    float4 a0 = xp[0], a1 = xp[1];
    const float4* wp = (const float4*)(W + (size_t)(n0 + row) * 256 + k0 + kq);
    float4 b0 = wp[0], b1 = wp[1];
    As[row][kq+0]=a0.x; As[row][kq+1]=a0.y; As[row][kq+2]=a0.z; As[row][kq+3]=a0.w;
    As[row][kq+4]=a1.x; As[row][kq+5]=a1.y; As[row][kq+6]=a1.z; As[row][kq+7]=a1.w;
    Bs[row][kq+0]=b0.x; Bs[row][kq+1]=b0.y; Bs[row][kq+2]=b0.z; Bs[row][kq+3]=b0.w;
    Bs[row][kq+4]=b1.x; Bs[row][kq+5]=b1.y; Bs[row][kq+6]=b1.z; Bs[row][kq+7]=b1.w;
    __syncthreads();
    #pragma unroll
    for (int k = 0; k < 32; ++k) {
      float a[4], bv[4];
      #pragma unroll
      for (int i = 0; i < 4; ++i) a[i] = As[ty*4+i][k];
      #pragma unroll
      for (int j = 0; j < 4; ++j) bv[j] = Bs[tx*4+j][k];
      #pragma unroll
      for (int i = 0; i < 4; ++i)
        #pragma unroll
        for (int j = 0; j < 4; ++j) acc[i][j] += a[i] * bv[j];
    }
    __syncthreads();
  }
  #pragma unroll
  for (int j = 0; j < 4; ++j) {
    const int n = n0 + tx*4 + j;
    const float bb = bias ? bias[n] : 0.0f;
    #pragma unroll
    for (int i = 0; i < 4; ++i)
      out[(size_t)(r0 + ty*4 + i) * N + n] = acc[i][j] + bb;
  }
}

// ---------------------------------------------------------------------------
// K projection with TRANSPOSED store: kT[b][n][m] (m contiguous), n = h*32+d.
// rows r = b*4096 + m.  grid = (512, 4)
// ---------------------------------------------------------------------------
__global__ __launch_bounds__(256) void gemm_kt(
    const float* __restrict__ X, const float* __restrict__ W,
    float* __restrict__ kT) {
  __shared__ float As[64][33];
  __shared__ float Bs[64][33];
  __shared__ float Ts[64][65];
  const int tid = threadIdx.x;
  const int r0 = blockIdx.x * 64, n0 = blockIdx.y * 64;
  const int row = tid & 63, kq = (tid >> 6) * 8;
  const int ty = tid >> 4, tx = tid & 15;
  float acc[4][4] = {};
  for (int k0 = 0; k0 < 256; k0 += 32) {
    const float4* xp = (const float4*)(X + (size_t)(r0 + row) * 256 + k0 + kq);
    float4 a0 = xp[0], a1 = xp[1];
    const float4* wp = (const float4*)(W + (size_t)(n0 + row) * 256 + k0 + kq);
    float4 b0 = wp[0], b1 = wp[1];
    As[row][kq+0]=a0.x; As[row][kq+1]=a0.y; As[row][kq+2]=a0.z; As[row][kq+3]=a0.w;
    As[row][kq+4]=a1.x; As[row][kq+5]=a1.y; As[row][kq+6]=a1.z; As[row][kq+7]=a1.w;
    Bs[row][kq+0]=b0.x; Bs[row][kq+1]=b0.y; Bs[row][kq+2]=b0.z; Bs[row][kq+3]=b0.w;
    Bs[row][kq+4]=b1.x; Bs[row][kq+5]=b1.y; Bs[row][kq+6]=b1.z; Bs[row][kq+7]=b1.w;
    __syncthreads();
    #pragma unroll
    for (int k = 0; k < 32; ++k) {
      float a[4], bv[4];
      #pragma unroll
      for (int i = 0; i < 4; ++i) a[i] = As[ty*4+i][k];
      #pragma unroll
      for (int j = 0; j < 4; ++j) bv[j] = Bs[tx*4+j][k];
      #pragma unroll
      for (int i = 0; i < 4; ++i)
        #pragma unroll
        for (int j = 0; j < 4; ++j) acc[i][j] += a[i] * bv[j];
    }
    __syncthreads();
  }
  // stage transposed tile: Ts[n_local][m_local]
  #pragma unroll
  for (int j = 0; j < 4; ++j)
    #pragma unroll
    for (int i = 0; i < 4; ++i)
      Ts[tx*4+j][ty*4+i] = acc[i][j];
  __syncthreads();
  const int b = r0 >> 12, m0 = r0 & 4095;
  #pragma unroll
  for (int rep = 0; rep < 4; ++rep) {
    const int nl = rep*16 + (tid >> 4);
    const int ml = (tid & 15) * 4;
    float4 v = *(const float4*)&Ts[nl][ml];
    *(float4*)&kT[((size_t)(b*256) + n0 + nl)*4096 + m0 + ml] = v;
  }
}

// ---------------------------------------------------------------------------
// f-projection: scatter n<256 -> vctx[b][n][hw] planar, n>=256 -> gates
// ---------------------------------------------------------------------------
__global__ __launch_bounds__(256) void gemm_f(
    const float* __restrict__ ctx, const float* __restrict__ fw,
    const float* __restrict__ fb, float* __restrict__ vctx,
    float* __restrict__ gates) {
  __shared__ float As[64][33];
  __shared__ float Bs[64][33];
  const int tid = threadIdx.x;
  const int r0 = blockIdx.x * 64, n0 = blockIdx.y * 64;
  const int row = tid & 63, kq = (tid >> 6) * 8;
  const int ty = tid >> 4, tx = tid & 15;
  float acc[4][4] = {};
  for (int k0 = 0; k0 < 256; k0 += 32) {
    const float4* xp = (const float4*)(ctx + (size_t)(r0 + row) * 256 + k0 + kq);
    float4 a0 = xp[0], a1 = xp[1];
    float4 b0 = make_float4(0.f,0.f,0.f,0.f), b1 = b0;
    if (n0 + row < 260) {
      const float4* wp = (const float4*)(fw + (size_t)(n0 + row) * 256 + k0 + kq);
      b0 = wp[0]; b1 = wp[1];
    }
    As[row][kq+0]=a0.x; As[row][kq+1]=a0.y; As[row][kq+2]=a0.z; As[row][kq+3]=a0.w;
    As[row][kq+4]=a1.x; As[row][kq+5]=a1.y; As[row][kq+6]=a1.z; As[row][kq+7]=a1.w;
    Bs[row][kq+0]=b0.x; Bs[row][kq+1]=b0.y; Bs[row][kq+2]=b0.z; Bs[row][kq+3]=b0.w;
    Bs[row][kq+4]=b1.x; Bs[row][kq+5]=b1.y; Bs[row][kq+6]=b1.z; Bs[row][kq+7]=b1.w;
    __syncthreads();
    #pragma unroll
    for (int k = 0; k < 32; ++k) {
      float a[4], bv[4];
      #pragma unroll
      for (int i = 0; i < 4; ++i) a[i] = As[ty*4+i][k];
      #pragma unroll
      for (int j = 0; j < 4; ++j) bv[j] = Bs[tx*4+j][k];
      #pragma unroll
      for (int i = 0; i < 4; ++i)
        #pragma unroll
        for (int j = 0; j < 4; ++j) acc[i][j] += a[i] * bv[j];
    }
    __syncthreads();
  }
  #pragma unroll
  for (int j = 0; j < 4; ++j) {
    const int n = n0 + tx*4 + j;
    if (n >= 260) continue;
    const float bb = fb[n];
    #pragma unroll
    for (int i = 0; i < 4; ++i) {
      const int r = r0 + ty*4 + i;
      const int b = r >> 12, hw = r & 4095;
      const float v = acc[i][j] + bb;
      if (n < 256) vctx[((size_t)(b*256 + n)) * 4096 + hw] = v;
      else         gates[((size_t)(b*4 + (n - 256))) * 4096 + hw] = v;
    }
  }
}

// ---------------------------------------------------------------------------
// Depthwise conv + GELU, one (b,c) 64x64 plane per block. grid = 2048
// ---------------------------------------------------------------------------
template<int KK, int LYR, bool FIRST>
__global__ __launch_bounds__(256) void dwconv(
    const float* __restrict__ in, const float* __restrict__ wk,
    const float* __restrict__ gates, float* __restrict__ outv,
    float* __restrict__ vall) {
  constexpr int P = KK / 2, TW = 64 + 2 * P;
  __shared__ float tile[TW * TW];
  __shared__ float wsh[KK * KK];
  const int tid = threadIdx.x;
  const int b = blockIdx.x >> 8, c = blockIdx.x & 255;
  const float* ip = in + (size_t)(b*256 + c) * 4096;
  if (tid < KK*KK) wsh[tid] = wk[c*KK*KK + tid];
  for (int idx = tid; idx < TW*TW; idx += 256) {
    const int ty = idx / TW, tx = idx - ty*TW;
    const int gy = ty - P, gx = tx - P;
    tile[idx] = (gy >= 0 && gy < 64 && gx >= 0 && gx < 64) ? ip[gy*64 + gx] : 0.0f;
  }
  __syncthreads();
  const float* gl = gates + (size_t)(b*4 + LYR) * 4096;
  float* vp = vall + (size_t)(b*256 + c) * 4096;
  float* op = outv + (size_t)(b*256 + c) * 4096;
  #pragma unroll
  for (int ii = 0; ii < 16; ++ii) {
    const int pix = ii*256 + tid;
    const int y = pix >> 6, x = pix & 63;
    float acc = 0.f;
    #pragma unroll
    for (int ky = 0; ky < KK; ++ky)
      #pragma unroll
      for (int kx = 0; kx < KK; ++kx)
        acc += wsh[ky*KK + kx] * tile[(y+ky)*TW + (x+kx)];
    const float g = gelu_f(acc);
    op[pix] = g;
    const float t = g * gl[pix];
    if (FIRST) vp[pix] = t; else vp[pix] += t;
  }
}

// Last conv (k=7, layer 2) + global-mean term.
__global__ __launch_bounds__(256) void dwconv7(
    const float* __restrict__ in, const float* __restrict__ wk,
    const float* __restrict__ gates, float* __restrict__ vall) {
  constexpr int KK = 7, P = 3, TW = 70;
  __shared__ float tile[TW * TW];
  __shared__ float wsh[KK * KK];
  __shared__ float red[4];
  const int tid = threadIdx.x;
  const int b = blockIdx.x >> 8, c = blockIdx.x & 255;
  const float* ip = in + (size_t)(b*256 + c) * 4096;
  if (tid < KK*KK) wsh[tid] = wk[c*KK*KK + tid];
  for (int idx = tid; idx < TW*TW; idx += 256) {
    const int ty = idx / TW, tx = idx - ty*TW;
    const int gy = ty - P, gx = tx - P;
    tile[idx] = (gy >= 0 && gy < 64 && gx >= 0 && gx < 64) ? ip[gy*64 + gx] : 0.0f;
  }
  __syncthreads();
  float gv[16];
  #pragma unroll
  for (int ii = 0; ii < 16; ++ii) {
    const int pix = ii*256 + tid;
    const int y = pix >> 6, x = pix & 63;
    float acc = 0.f;
    #pragma unroll
    for (int ky = 0; ky < KK; ++ky)
      #pragma unroll
      for (int kx = 0; kx < KK; ++kx)
        acc += wsh[ky*KK + kx] * tile[(y+ky)*TW + (x+kx)];
    gv[ii] = gelu_f(acc);
  }
  float s = 0.f;
  #pragma unroll
  for (int ii = 0; ii < 16; ++ii) s += gv[ii];
  #pragma unroll
  for (int off = 32; off >= 1; off >>= 1) s += __shfl_xor(s, off, 64);
  if ((tid & 63) == 0) red[tid >> 6] = s;
  __syncthreads();
  const float vg = gelu_f((red[0]+red[1]+red[2]+red[3]) * (1.0f/4096.0f));
  const float* g2 = gates + (size_t)(b*4 + 2) * 4096;
  const float* g3 = gates + (size_t)(b*4 + 3) * 4096;
  float* vp = vall + (size_t)(b*256 + c) * 4096;
  #pragma unroll
  for (int ii = 0; ii < 16; ++ii) {
    const int pix = ii*256 + tid;
    vp[pix] += gv[ii]*g2[pix] + vg*g3[pix];
  }
}

// ---------------------------------------------------------------------------
// h-GEMM: v_mod[b,d,hw] = sum_c h_w[d,c]*v_all[b,c,hw] + h_b[d]
// written permuted: vlin[b][m = d*16 + hw/256][col = hw%256]
// ---------------------------------------------------------------------------
__global__ __launch_bounds__(256) void gemm_h(
    const float* __restrict__ vall, const float* __restrict__ hwm,
    const float* __restrict__ hb, float* __restrict__ vlin) {
  __shared__ float As[32][65];   // [c][hw]
  __shared__ float Bs[64][33];   // [d][c]
  const int tid = threadIdx.x;
  const int hw0 = blockIdx.x * 64, d0 = blockIdx.y * 64, b = blockIdx.z;
  const int ty = tid >> 4, tx = tid & 15;
  float acc[4][4] = {};
  for (int c0 = 0; c0 < 256; c0 += 32) {
    const int cc = tid >> 3, hwi = (tid & 7) * 8;
    const float4* vp = (const float4*)(vall + (size_t)(b*256 + c0 + cc)*4096 + hw0 + hwi);
    float4 a0 = vp[0], a1 = vp[1];
    As[cc][hwi+0]=a0.x; As[cc][hwi+1]=a0.y; As[cc][hwi+2]=a0.z; As[cc][hwi+3]=a0.w;
    As[cc][hwi+4]=a1.x; As[cc][hwi+5]=a1.y; As[cc][hwi+6]=a1.z; As[cc][hwi+7]=a1.w;
    const int dd = tid & 63, cq = (tid >> 6) * 8;
    const float4* wp = (const float4*)(hwm + (size_t)(d0 + dd)*256 + c0 + cq);
    float4 b0 = wp[0], b1 = wp[1];
    Bs[dd][cq+0]=b0.x; Bs[dd][cq+1]=b0.y; Bs[dd][cq+2]=b0.z; Bs[dd][cq+3]=b0.w;
    Bs[dd][cq+4]=b1.x; Bs[dd][cq+5]=b1.y; Bs[dd][cq+6]=b1.z; Bs[dd][cq+7]=b1.w;
    __syncthreads();
    #pragma unroll
    for (int k = 0; k < 32; ++k) {
      float a[4], bv[4];
      #pragma unroll
      for (int i = 0; i < 4; ++i) a[i] = As[k][ty*4+i];
      #pragma unroll
      for (int j = 0; j < 4; ++j) bv[j] = Bs[tx*4+j][k];
      #pragma unroll
      for (int i = 0; i < 4; ++i)
        #pragma unroll
        for (int j = 0; j < 4; ++j) acc[i][j] += a[i] * bv[j];
    }
    __syncthreads();
  }
  #pragma unroll
  for (int j = 0; j < 4; ++j) {
    const int d = d0 + tx*4 + j;
    const float bb = hb[d];
    #pragma unroll
    for (int i = 0; i < 4; ++i) {
      const int hw = hw0 + ty*4 + i;
      const int m = d*16 + (hw >> 8);
      vlin[((size_t)b*4096 + m)*256 + (hw & 255)] = acc[i][j] + bb;
    }
  }
}

// ---------------------------------------------------------------------------
// Attention v2: outer-product form on kT[b][h*32+d][m] (m contiguous).
// One block = 8 q-rows of one (b,h). grid = 2048, decode bh = blk & 63 so all
// n-tiles of one (b,h) land on the same XCD (blk % 8 == bh % 8).
// ---------------------------------------------------------------------------
__global__ __launch_bounds__(256) void attn_softmax2(
    const float* __restrict__ q, const float* __restrict__ kT,
    float* __restrict__ attn) {
  const int blk = blockIdx.x;
  const int bh = blk & 63, nt = blk >> 6;
  const int b = bh >> 3, h = bh & 7;
  const int n0 = nt * 8;
  const int tid = threadIdx.x;
  __shared__ float qs[8][32];
  __shared__ float red[8][4];
  {
    const int r = tid >> 5, d = tid & 31;
    qs[r][d] = q[(size_t)(b*256 + n0 + r)*256 + h*32 + d];
  }
  __syncthreads();
  const float* kbase = kT + ((size_t)(b*256) + h*32) * 4096;
  float acc[8][16] = {};
  #pragma unroll 2
  for (int d = 0; d < 32; ++d) {
    const float4* kp = (const float4*)(kbase + (size_t)d*4096) + tid;
    const float4 k0 = kp[0], k1 = kp[256], k2 = kp[512], k3 = kp[768];
    #pragma unroll
    for (int r = 0; r < 8; ++r) {
      const float qv = qs[r][d];
      acc[r][ 0] += qv*k0.x; acc[r][ 1] += qv*k0.y; acc[r][ 2] += qv*k0.z; acc[r][ 3] += qv*k0.w;
      acc[r][ 4] += qv*k1.x; acc[r][ 5] += qv*k1.y; acc[r][ 6] += qv*k1.z; acc[r][ 7] += qv*k1.w;
      acc[r][ 8] += qv*k2.x; acc[r][ 9] += qv*k2.y; acc[r][10] += qv*k2.z; acc[r][11] += qv*k2.w;
      acc[r][12] += qv*k3.x; acc[r][13] += qv*k3.y; acc[r][14] += qv*k3.z; acc[r][15] += qv*k3.w;
    }
  }
  // exp (logits tiny: no max subtraction needed) and row sums
  #pragma unroll
  for (int r = 0; r < 8; ++r)
    #pragma unroll
    for (int i = 0; i < 16; ++i)
      acc[r][i] = __expf(acc[r][i] * CSCALE);
  #pragma unroll
  for (int r = 0; r < 8; ++r) {
    float t = 0.f;
    #pragma unroll
    for (int i = 0; i < 16; ++i) t += acc[r][i];
    #pragma unroll
    for (int off = 32; off >= 1; off >>= 1) t += __shfl_xor(t, off, 64);
    if ((tid & 63) == 0) red[r][tid >> 6] = t;
  }
  __syncthreads();
  float* ab = attn + ((size_t)(bh*256) + n0) * 4096;
  #pragma unroll
  for (int r = 0; r < 8; ++r) {
    const float invS = 1.0f / (red[r][0] + red[r][1] + red[r][2] + red[r][3]);
    float4* op = (float4*)(ab + (size_t)r*4096) + tid;
    #pragma unroll
    for (int qq = 0; qq < 4; ++qq) {
      float4 o;
      o.x = acc[r][qq*4+0] * invS;
      o.y = acc[r][qq*4+1] * invS;
      o.z = acc[r][qq*4+2] * invS;
      o.w = acc[r][qq*4+3] * invS;
      op[qq*256] = o;
    }
  }
}

// ---------------------------------------------------------------------------
// PV: out[b,h,n,d] = sum_m attn[b,h,n,m] * vlin[b,m,h*32+d]
// ---------------------------------------------------------------------------
__global__ __launch_bounds__(256) void pv_gemm(
    const float* __restrict__ attn, const float* __restrict__ vlin,
    float* __restrict__ outs) {
  __shared__ float As[64][65];  // n x m-chunk
  __shared__ float Bs[64][33];  // m x d
  const int tid = threadIdx.x;
  const int n0 = blockIdx.x * 64;
  const int bh = blockIdx.y, b = bh >> 3, h = bh & 7;
  const int ty = tid >> 4, tx = tid & 15;
  float acc[4][2] = {};
  const float* ab = attn + ((size_t)bh*256 + n0) * 4096;
  const float* vb = vlin + (size_t)b*4096*256 + h*32;
  for (int m0 = 0; m0 < 4096; m0 += 64) {
    const int rr = tid >> 2, mi = (tid & 3) * 16;
    const float4* ap = (const float4*)(ab + (size_t)rr*4096 + m0 + mi);
    float4 a0 = ap[0], a1 = ap[1], a2 = ap[2], a3 = ap[3];
    As[rr][mi+ 0]=a0.x; As[rr][mi+ 1]=a0.y; As[rr][mi+ 2]=a0.z; As[rr][mi+ 3]=a0.w;
    As[rr][mi+ 4]=a1.x; As[rr][mi+ 5]=a1.y; As[rr][mi+ 6]=a1.z; As[rr][mi+ 7]=a1.w;
    As[rr][mi+ 8]=a2.x; As[rr][mi+ 9]=a2.y; As[rr][mi+10]=a2.z; As[rr][mi+11]=a2.w;
    As[rr][mi+12]=a3.x; As[rr][mi+13]=a3.y; As[rr][mi+14]=a3.z; As[rr][mi+15]=a3.w;
    const int mm = tid >> 2, dq = (tid & 3) * 8;   // 128B-coalesced V load
    const float4* vp = (const float4*)(vb + (size_t)(m0 + mm)*256 + dq);
    float4 b0 = vp[0], b1 = vp[1];
    Bs[mm][dq+0]=b0.x; Bs[mm][dq+1]=b0.y; Bs[mm][dq+2]=b0.z; Bs[mm][dq+3]=b0.w;
    Bs[mm][dq+4]=b1.x; Bs[mm][dq+5]=b1.y; Bs[mm][dq+6]=b1.z; Bs[mm][dq+7]=b1.w;
    __syncthreads();
    #pragma unroll
    for (int kk = 0; kk < 64; ++kk) {
      float a[4];
      #pragma unroll
      for (int i = 0; i < 4; ++i) a[i] = As[ty*4+i][kk];
      const float v0 = Bs[kk][tx*2+0], v1 = Bs[kk][tx*2+1];
      #pragma unroll
      for (int i = 0; i < 4; ++i) { acc[i][0] += a[i]*v0; acc[i][1] += a[i]*v1; }
    }
    __syncthreads();
  }
  #pragma unroll
  for (int i = 0; i < 4; ++i)
    #pragma unroll
    for (int j = 0; j < 2; ++j)
      outs[(size_t)(b*256 + n0 + ty*4 + i)*256 + h*32 + tx*2 + j] = acc[i][j];
}

} // namespace

extern "C" void kernel_launch(void* const* d_in, const int* in_sizes, int n_in,
                              void* d_out, int out_size, void* d_ws, size_t ws_size,
                              hipStream_t stream) {
  (void)in_sizes; (void)n_in; (void)out_size; (void)ws_size;
  const float* latents = (const float*)d_in[0];
  const float* context = (const float*)d_in[1];
  const float* q_w    = (const float*)d_in[2];
  const float* k_w    = (const float*)d_in[3];
  const float* f_w    = (const float*)d_in[4];
  const float* f_b    = (const float*)d_in[5];
  const float* h_w    = (const float*)d_in[6];
  const float* h_b    = (const float*)d_in[7];
  const float* fk0    = (const float*)d_in[8];
  const float* fk1    = (const float*)d_in[9];
  const float* fk2    = (const float*)d_in[10];
  const float* proj_w = (const float*)d_in[11];
  const float* proj_b = (const float*)d_in[12];

  float* out0 = (float*)d_out;                  // (8,256,256)
  float* attn = out0 + (size_t)8*256*256;       // (8,8,256,4096)

  // workspace layout (floats)
  float* w    = (float*)d_ws;
  float* qb    = w;                       // 524288
  float* kTb   = qb   + 524288;           // 8388608  (transposed K: [b][c][m])
  float* buf1  = kTb  + 8388608;          // 8388608
  float* buf2  = buf1 + 8388608;          // 8388608
  float* gates = buf2 + 8388608;          // 131072
  float* vall  = gates + 131072;          // 8388608
  float* aout  = vall + 8388608;          // 524288
  float* vlin  = buf2;                    // alias: buf2 dead after conv5

  gemm_xwt<<<dim3(32, 4),  256, 0, stream>>>(latents, q_w, nullptr, qb, 256);
  gemm_kt <<<dim3(512, 4), 256, 0, stream>>>(context, k_w, kTb);
  gemm_f  <<<dim3(512, 5), 256, 0, stream>>>(context, f_w, f_b, buf1, gates);
  dwconv<3, 0, true ><<<2048, 256, 0, stream>>>(buf1, fk0, gates, buf2, vall);
  dwconv<5, 1, false><<<2048, 256, 0, stream>>>(buf2, fk1, gates, buf1, vall);
  dwconv7            <<<2048, 256, 0, stream>>>(buf1, fk2, gates, vall);
  gemm_h  <<<dim3(64, 4, 8), 256, 0, stream>>>(vall, h_w, h_b, vlin);
  attn_softmax2<<<2048, 256, 0, stream>>>(qb, kTb, attn);
  pv_gemm <<<dim3(4, 64), 256, 0, stream>>>(attn, vlin, aout);
  gemm_xwt<<<dim3(32, 4), 256, 0, stream>>>(aout, proj_w, proj_b, out0, 256);
}

// Round 3
// 664.684 us; speedup vs baseline: 1.7687x; 1.1107x over previous
//
#include <hip/hip_runtime.h>
#include <math.h>

// Shapes: B=8, N_L=256, C=256, NH=8, HD=32, H=W=64, N_C=4096, L=3, KS={3,5,7}
// SCALE = 1/sqrt(32)

namespace {

constexpr float CSCALE = 0.17677669529663688f;

__device__ __forceinline__ float gelu_f(float x) {
  return 0.5f * x * (1.0f + erff(x * 0.70710678118654752f));
}

// ---------------------------------------------------------------------------
// Generic GEMM: out[r][n] = sum_k X[r][k] * W[n][k] + bias[n]   (K = 256)
// ---------------------------------------------------------------------------
__global__ __launch_bounds__(256) void gemm_xwt(
    const float* __restrict__ X, const float* __restrict__ W,
    const float* __restrict__ bias, float* __restrict__ out, int N) {
  __shared__ float As[64][33];
  __shared__ float Bs[64][33];
  const int tid = threadIdx.x;
  const int r0 = blockIdx.x * 64, n0 = blockIdx.y * 64;
  const int row = tid & 63, kq = (tid >> 6) * 8;
  const int ty = tid >> 4, tx = tid & 15;
  float acc[4][4] = {};
  for (int k0 = 0; k0 < 256; k0 += 32) {
    const float4* xp = (const float4*)(X + (size_t)(r0 + row) * 256 + k0 + kq);
    float4 a0 = xp[0], a1 = xp[1];
    const float4* wp = (const float4*)(W + (size_t)(n0 + row) * 256 + k0 + kq);
    float4 b0 = wp[0], b1 = wp[1];
    As[row][kq+0]=a0.x; As[row][kq+1]=a0.y; As[row][kq+2]=a0.z; As[row][kq+3]=a0.w;
    As[row][kq+4]=a1.x; As[row][kq+5]=a1.y; As[row][kq+6]=a1.z; As[row][kq+7]=a1.w;
    Bs[row][kq+0]=b0.x; Bs[row][kq+1]=b0.y; Bs[row][kq+2]=b0.z; Bs[row][kq+3]=b0.w;
    Bs[row][kq+4]=b1.x; Bs[row][kq+5]=b1.y; Bs[row][kq+6]=b1.z; Bs[row][kq+7]=b1.w;
    __syncthreads();
    #pragma unroll
    for (int k = 0; k < 32; ++k) {
      float a[4], bv[4];
      #pragma unroll
      for (int i = 0; i < 4; ++i) a[i] = As[ty*4+i][k];
      #pragma unroll
      for (int j = 0; j < 4; ++j) bv[j] = Bs[tx*4+j][k];
      #pragma unroll
      for (int i = 0; i < 4; ++i)
        #pragma unroll
        for (int j = 0; j < 4; ++j) acc[i][j] += a[i] * bv[j];
    }
    __syncthreads();
  }
  #pragma unroll
  for (int j = 0; j < 4; ++j) {
    const int n = n0 + tx*4 + j;
    const float bb = bias ? bias[n] : 0.0f;
    #pragma unroll
    for (int i = 0; i < 4; ++i)
      out[(size_t)(r0 + ty*4 + i) * N + n] = acc[i][j] + bb;
  }
}

// ---------------------------------------------------------------------------
// K projection with TRANSPOSED store: kT[b][n][m] (m contiguous), n = h*32+d.
// ---------------------------------------------------------------------------
__global__ __launch_bounds__(256) void gemm_kt(
    const float* __restrict__ X, const float* __restrict__ W,
    float* __restrict__ kT) {
  __shared__ float As[64][33];
  __shared__ float Bs[64][33];
  __shared__ float Ts[64][65];
  const int tid = threadIdx.x;
  const int r0 = blockIdx.x * 64, n0 = blockIdx.y * 64;
  const int row = tid & 63, kq = (tid >> 6) * 8;
  const int ty = tid >> 4, tx = tid & 15;
  float acc[4][4] = {};
  for (int k0 = 0; k0 < 256; k0 += 32) {
    const float4* xp = (const float4*)(X + (size_t)(r0 + row) * 256 + k0 + kq);
    float4 a0 = xp[0], a1 = xp[1];
    const float4* wp = (const float4*)(W + (size_t)(n0 + row) * 256 + k0 + kq);
    float4 b0 = wp[0], b1 = wp[1];
    As[row][kq+0]=a0.x; As[row][kq+1]=a0.y; As[row][kq+2]=a0.z; As[row][kq+3]=a0.w;
    As[row][kq+4]=a1.x; As[row][kq+5]=a1.y; As[row][kq+6]=a1.z; As[row][kq+7]=a1.w;
    Bs[row][kq+0]=b0.x; Bs[row][kq+1]=b0.y; Bs[row][kq+2]=b0.z; Bs[row][kq+3]=b0.w;
    Bs[row][kq+4]=b1.x; Bs[row][kq+5]=b1.y; Bs[row][kq+6]=b1.z; Bs[row][kq+7]=b1.w;
    __syncthreads();
    #pragma unroll
    for (int k = 0; k < 32; ++k) {
      float a[4], bv[4];
      #pragma unroll
      for (int i = 0; i < 4; ++i) a[i] = As[ty*4+i][k];
      #pragma unroll
      for (int j = 0; j < 4; ++j) bv[j] = Bs[tx*4+j][k];
      #pragma unroll
      for (int i = 0; i < 4; ++i)
        #pragma unroll
        for (int j = 0; j < 4; ++j) acc[i][j] += a[i] * bv[j];
    }
    __syncthreads();
  }
  #pragma unroll
  for (int j = 0; j < 4; ++j)
    #pragma unroll
    for (int i = 0; i < 4; ++i)
      Ts[tx*4+j][ty*4+i] = acc[i][j];
  __syncthreads();
  const int b = r0 >> 12, m0 = r0 & 4095;
  #pragma unroll
  for (int rep = 0; rep < 4; ++rep) {
    const int nl = rep*16 + (tid >> 4);
    const int ml = (tid & 15) * 4;
    float4 v = *(const float4*)&Ts[nl][ml];
    *(float4*)&kT[((size_t)(b*256) + n0 + nl)*4096 + m0 + ml] = v;
  }
}

// ---------------------------------------------------------------------------
// f-projection: scatter n<256 -> vctx[b][n][hw] planar, n>=256 -> gates
// ---------------------------------------------------------------------------
__global__ __launch_bounds__(256) void gemm_f(
    const float* __restrict__ ctx, const float* __restrict__ fw,
    const float* __restrict__ fb, float* __restrict__ vctx,
    float* __restrict__ gates) {
  __shared__ float As[64][33];
  __shared__ float Bs[64][33];
  const int tid = threadIdx.x;
  const int r0 = blockIdx.x * 64, n0 = blockIdx.y * 64;
  const int row = tid & 63, kq = (tid >> 6) * 8;
  const int ty = tid >> 4, tx = tid & 15;
  float acc[4][4] = {};
  for (int k0 = 0; k0 < 256; k0 += 32) {
    const float4* xp = (const float4*)(ctx + (size_t)(r0 + row) * 256 + k0 + kq);
    float4 a0 = xp[0], a1 = xp[1];
    float4 b0 = make_float4(0.f,0.f,0.f,0.f), b1 = b0;
    if (n0 + row < 260) {
      const float4* wp = (const float4*)(fw + (size_t)(n0 + row) * 256 + k0 + kq);
      b0 = wp[0]; b1 = wp[1];
    }
    As[row][kq+0]=a0.x; As[row][kq+1]=a0.y; As[row][kq+2]=a0.z; As[row][kq+3]=a0.w;
    As[row][kq+4]=a1.x; As[row][kq+5]=a1.y; As[row][kq+6]=a1.z; As[row][kq+7]=a1.w;
    Bs[row][kq+0]=b0.x; Bs[row][kq+1]=b0.y; Bs[row][kq+2]=b0.z; Bs[row][kq+3]=b0.w;
    Bs[row][kq+4]=b1.x; Bs[row][kq+5]=b1.y; Bs[row][kq+6]=b1.z; Bs[row][kq+7]=b1.w;
    __syncthreads();
    #pragma unroll
    for (int k = 0; k < 32; ++k) {
      float a[4], bv[4];
      #pragma unroll
      for (int i = 0; i < 4; ++i) a[i] = As[ty*4+i][k];
      #pragma unroll
      for (int j = 0; j < 4; ++j) bv[j] = Bs[tx*4+j][k];
      #pragma unroll
      for (int i = 0; i < 4; ++i)
        #pragma unroll
        for (int j = 0; j < 4; ++j) acc[i][j] += a[i] * bv[j];
    }
    __syncthreads();
  }
  #pragma unroll
  for (int j = 0; j < 4; ++j) {
    const int n = n0 + tx*4 + j;
    if (n >= 260) continue;
    const float bb = fb[n];
    #pragma unroll
    for (int i = 0; i < 4; ++i) {
      const int r = r0 + ty*4 + i;
      const int b = r >> 12, hw = r & 4095;
      const float v = acc[i][j] + bb;
      if (n < 256) vctx[((size_t)(b*256 + n)) * 4096 + hw] = v;
      else         gates[((size_t)(b*4 + (n - 256))) * 4096 + hw] = v;
    }
  }
}

// ---------------------------------------------------------------------------
// Depthwise conv + GELU, one (b,c) 64x64 plane per block. grid = 2048
// ---------------------------------------------------------------------------
template<int KK, int LYR, bool FIRST>
__global__ __launch_bounds__(256) void dwconv(
    const float* __restrict__ in, const float* __restrict__ wk,
    const float* __restrict__ gates, float* __restrict__ outv,
    float* __restrict__ vall) {
  constexpr int P = KK / 2, TW = 64 + 2 * P;
  __shared__ float tile[TW * TW];
  __shared__ float wsh[KK * KK];
  const int tid = threadIdx.x;
  const int b = blockIdx.x >> 8, c = blockIdx.x & 255;
  const float* ip = in + (size_t)(b*256 + c) * 4096;
  if (tid < KK*KK) wsh[tid] = wk[c*KK*KK + tid];
  for (int idx = tid; idx < TW*TW; idx += 256) {
    const int ty = idx / TW, tx = idx - ty*TW;
    const int gy = ty - P, gx = tx - P;
    tile[idx] = (gy >= 0 && gy < 64 && gx >= 0 && gx < 64) ? ip[gy*64 + gx] : 0.0f;
  }
  __syncthreads();
  const float* gl = gates + (size_t)(b*4 + LYR) * 4096;
  float* vp = vall + (size_t)(b*256 + c) * 4096;
  float* op = outv + (size_t)(b*256 + c) * 4096;
  #pragma unroll
  for (int ii = 0; ii < 16; ++ii) {
    const int pix = ii*256 + tid;
    const int y = pix >> 6, x = pix & 63;
    float acc = 0.f;
    #pragma unroll
    for (int ky = 0; ky < KK; ++ky)
      #pragma unroll
      for (int kx = 0; kx < KK; ++kx)
        acc += wsh[ky*KK + kx] * tile[(y+ky)*TW + (x+kx)];
    const float g = gelu_f(acc);
    op[pix] = g;
    const float t = g * gl[pix];
    if (FIRST) vp[pix] = t; else vp[pix] += t;
  }
}

// Last conv (k=7, layer 2) + global-mean term.
__global__ __launch_bounds__(256) void dwconv7(
    const float* __restrict__ in, const float* __restrict__ wk,
    const float* __restrict__ gates, float* __restrict__ vall) {
  constexpr int KK = 7, P = 3, TW = 70;
  __shared__ float tile[TW * TW];
  __shared__ float wsh[KK * KK];
  __shared__ float red[4];
  const int tid = threadIdx.x;
  const int b = blockIdx.x >> 8, c = blockIdx.x & 255;
  const float* ip = in + (size_t)(b*256 + c) * 4096;
  if (tid < KK*KK) wsh[tid] = wk[c*KK*KK + tid];
  for (int idx = tid; idx < TW*TW; idx += 256) {
    const int ty = idx / TW, tx = idx - ty*TW;
    const int gy = ty - P, gx = tx - P;
    tile[idx] = (gy >= 0 && gy < 64 && gx >= 0 && gx < 64) ? ip[gy*64 + gx] : 0.0f;
  }
  __syncthreads();
  float gv[16];
  #pragma unroll
  for (int ii = 0; ii < 16; ++ii) {
    const int pix = ii*256 + tid;
    const int y = pix >> 6, x = pix & 63;
    float acc = 0.f;
    #pragma unroll
    for (int ky = 0; ky < KK; ++ky)
      #pragma unroll
      for (int kx = 0; kx < KK; ++kx)
        acc += wsh[ky*KK + kx] * tile[(y+ky)*TW + (x+kx)];
    gv[ii] = gelu_f(acc);
  }
  float s = 0.f;
  #pragma unroll
  for (int ii = 0; ii < 16; ++ii) s += gv[ii];
  #pragma unroll
  for (int off = 32; off >= 1; off >>= 1) s += __shfl_xor(s, off, 64);
  if ((tid & 63) == 0) red[tid >> 6] = s;
  __syncthreads();
  const float vg = gelu_f((red[0]+red[1]+red[2]+red[3]) * (1.0f/4096.0f));
  const float* g2 = gates + (size_t)(b*4 + 2) * 4096;
  const float* g3 = gates + (size_t)(b*4 + 3) * 4096;
  float* vp = vall + (size_t)(b*256 + c) * 4096;
  #pragma unroll
  for (int ii = 0; ii < 16; ++ii) {
    const int pix = ii*256 + tid;
    vp[pix] += gv[ii]*g2[pix] + vg*g3[pix];
  }
}

// ---------------------------------------------------------------------------
// h-GEMM: v_mod[b,d,hw] = sum_c h_w[d,c]*v_all[b,c,hw] + h_b[d]
// written permuted: vlin[b][m = d*16 + hw/256][col = hw%256]
// ---------------------------------------------------------------------------
__global__ __launch_bounds__(256) void gemm_h(
    const float* __restrict__ vall, const float* __restrict__ hwm,
    const float* __restrict__ hb, float* __restrict__ vlin) {
  __shared__ float As[32][65];   // [c][hw]
  __shared__ float Bs[64][33];   // [d][c]
  const int tid = threadIdx.x;
  const int hw0 = blockIdx.x * 64, d0 = blockIdx.y * 64, b = blockIdx.z;
  const int ty = tid >> 4, tx = tid & 15;
  float acc[4][4] = {};
  for (int c0 = 0; c0 < 256; c0 += 32) {
    const int cc = tid >> 3, hwi = (tid & 7) * 8;
    const float4* vp = (const float4*)(vall + (size_t)(b*256 + c0 + cc)*4096 + hw0 + hwi);
    float4 a0 = vp[0], a1 = vp[1];
    As[cc][hwi+0]=a0.x; As[cc][hwi+1]=a0.y; As[cc][hwi+2]=a0.z; As[cc][hwi+3]=a0.w;
    As[cc][hwi+4]=a1.x; As[cc][hwi+5]=a1.y; As[cc][hwi+6]=a1.z; As[cc][hwi+7]=a1.w;
    const int dd = tid & 63, cq = (tid >> 6) * 8;
    const float4* wp = (const float4*)(hwm + (size_t)(d0 + dd)*256 + c0 + cq);
    float4 b0 = wp[0], b1 = wp[1];
    Bs[dd][cq+0]=b0.x; Bs[dd][cq+1]=b0.y; Bs[dd][cq+2]=b0.z; Bs[dd][cq+3]=b0.w;
    Bs[dd][cq+4]=b1.x; Bs[dd][cq+5]=b1.y; Bs[dd][cq+6]=b1.z; Bs[dd][cq+7]=b1.w;
    __syncthreads();
    #pragma unroll
    for (int k = 0; k < 32; ++k) {
      float a[4], bv[4];
      #pragma unroll
      for (int i = 0; i < 4; ++i) a[i] = As[k][ty*4+i];
      #pragma unroll
      for (int j = 0; j < 4; ++j) bv[j] = Bs[tx*4+j][k];
      #pragma unroll
      for (int i = 0; i < 4; ++i)
        #pragma unroll
        for (int j = 0; j < 4; ++j) acc[i][j] += a[i] * bv[j];
    }
    __syncthreads();
  }
  #pragma unroll
  for (int j = 0; j < 4; ++j) {
    const int d = d0 + tx*4 + j;
    const float bb = hb[d];
    #pragma unroll
    for (int i = 0; i < 4; ++i) {
      const int hw = hw0 + ty*4 + i;
      const int m = d*16 + (hw >> 8);
      vlin[((size_t)b*4096 + m)*256 + (hw & 255)] = acc[i][j] + bb;
    }
  }
}

// ---------------------------------------------------------------------------
// Attention: outer-product form on kT[b][h*32+d][m] (m contiguous).
// One block = 8 q-rows of one (b,h). grid = 2048, bh = blk & 63 (XCD locality)
// ---------------------------------------------------------------------------
__global__ __launch_bounds__(256) void attn_softmax2(
    const float* __restrict__ q, const float* __restrict__ kT,
    float* __restrict__ attn) {
  const int blk = blockIdx.x;
  const int bh = blk & 63, nt = blk >> 6;
  const int b = bh >> 3, h = bh & 7;
  const int n0 = nt * 8;
  const int tid = threadIdx.x;
  __shared__ float qs[8][32];
  __shared__ float red[8][4];
  {
    const int r = tid >> 5, d = tid & 31;
    qs[r][d] = q[(size_t)(b*256 + n0 + r)*256 + h*32 + d];
  }
  __syncthreads();
  const float* kbase = kT + ((size_t)(b*256) + h*32) * 4096;
  float acc[8][16] = {};
  #pragma unroll 2
  for (int d = 0; d < 32; ++d) {
    const float4* kp = (const float4*)(kbase + (size_t)d*4096) + tid;
    const float4 k0 = kp[0], k1 = kp[256], k2 = kp[512], k3 = kp[768];
    #pragma unroll
    for (int r = 0; r < 8; ++r) {
      const float qv = qs[r][d];
      acc[r][ 0] += qv*k0.x; acc[r][ 1] += qv*k0.y; acc[r][ 2] += qv*k0.z; acc[r][ 3] += qv*k0.w;
      acc[r][ 4] += qv*k1.x; acc[r][ 5] += qv*k1.y; acc[r][ 6] += qv*k1.z; acc[r][ 7] += qv*k1.w;
      acc[r][ 8] += qv*k2.x; acc[r][ 9] += qv*k2.y; acc[r][10] += qv*k2.z; acc[r][11] += qv*k2.w;
      acc[r][12] += qv*k3.x; acc[r][13] += qv*k3.y; acc[r][14] += qv*k3.z; acc[r][15] += qv*k3.w;
    }
  }
  #pragma unroll
  for (int r = 0; r < 8; ++r)
    #pragma unroll
    for (int i = 0; i < 16; ++i)
      acc[r][i] = __expf(acc[r][i] * CSCALE);
  #pragma unroll
  for (int r = 0; r < 8; ++r) {
    float t = 0.f;
    #pragma unroll
    for (int i = 0; i < 16; ++i) t += acc[r][i];
    #pragma unroll
    for (int off = 32; off >= 1; off >>= 1) t += __shfl_xor(t, off, 64);
    if ((tid & 63) == 0) red[r][tid >> 6] = t;
  }
  __syncthreads();
  float* ab = attn + ((size_t)(bh*256) + n0) * 4096;
  #pragma unroll
  for (int r = 0; r < 8; ++r) {
    const float invS = 1.0f / (red[r][0] + red[r][1] + red[r][2] + red[r][3]);
    float4* op = (float4*)(ab + (size_t)r*4096) + tid;
    #pragma unroll
    for (int qq = 0; qq < 4; ++qq) {
      float4 o;
      o.x = acc[r][qq*4+0] * invS;
      o.y = acc[r][qq*4+1] * invS;
      o.z = acc[r][qq*4+2] * invS;
      o.w = acc[r][qq*4+3] * invS;
      op[qq*256] = o;
    }
  }
}

// ---------------------------------------------------------------------------
// PV split-m: part[mc][b,n,h*32+d] = sum_{m in chunk} attn[bh,n,m]*vlin[b,m,h*32+d]
// grid = (2 n-tiles of 128, 64 bh, 8 m-chunks of 512). FMA-bound design:
// LDS As stored TRANSPOSED [m][row] so compute uses 2x ds_read_b128 / 16 FMA.
// ---------------------------------------------------------------------------
__global__ __launch_bounds__(256) void pv_split(
    const float* __restrict__ attn, const float* __restrict__ vlin,
    float* __restrict__ part) {
  __shared__ float As[64][132];  // [m_local][row], pad 132: f4-aligned, conflict-free
  __shared__ float Bs[64][36];   // [m_local][d]
  const int tid = threadIdx.x;
  const int n0 = blockIdx.x * 128;
  const int bh = blockIdx.y, b = bh >> 3, h = bh & 7;
  const int mc = blockIdx.z;
  const int ty = tid >> 3, tx = tid & 7;   // ty 0..31 (rows), tx 0..7 (cols)
  float acc[4][4] = {};
  const float* ab = attn + ((size_t)bh*256 + n0) * 4096;
  const float* vb = vlin + (size_t)b*4096*256 + h*32;
  const int row2 = tid >> 1, half = tid & 1;     // attn staging map
  const int vm = tid >> 2, dq = (tid & 3) * 8;   // V staging map
  for (int s = 0; s < 8; ++s) {
    const int m0 = mc*512 + s*64;
    // load attn rows (coalesced: 64 consecutive floats per row via 2 threads)
    const float4* ap = (const float4*)(ab + (size_t)row2*4096 + m0 + half*32);
    float4 av[8];
    #pragma unroll
    for (int qd = 0; qd < 8; ++qd) av[qd] = ap[qd];
    // load V tile rows
    const float4* vp = (const float4*)(vb + (size_t)(m0 + vm)*256 + dq);
    float4 v0 = vp[0], v1 = vp[1];
    __syncthreads();
    // transpose-write attn into As[m][row]  (2-way bank alias = free)
    #pragma unroll
    for (int qd = 0; qd < 8; ++qd) {
      const int ml = half*32 + qd*4;
      As[ml+0][row2] = av[qd].x;
      As[ml+1][row2] = av[qd].y;
      As[ml+2][row2] = av[qd].z;
      As[ml+3][row2] = av[qd].w;
    }
    Bs[vm][dq+0]=v0.x; Bs[vm][dq+1]=v0.y; Bs[vm][dq+2]=v0.z; Bs[vm][dq+3]=v0.w;
    Bs[vm][dq+4]=v1.x; Bs[vm][dq+5]=v1.y; Bs[vm][dq+6]=v1.z; Bs[vm][dq+7]=v1.w;
    __syncthreads();
    #pragma unroll
    for (int kk = 0; kk < 64; ++kk) {
      const float4 a = *(const float4*)&As[kk][ty*4];
      const float4 v = *(const float4*)&Bs[kk][tx*4];
      acc[0][0]+=a.x*v.x; acc[0][1]+=a.x*v.y; acc[0][2]+=a.x*v.z; acc[0][3]+=a.x*v.w;
      acc[1][0]+=a.y*v.x; acc[1][1]+=a.y*v.y; acc[1][2]+=a.y*v.z; acc[1][3]+=a.y*v.w;
      acc[2][0]+=a.z*v.x; acc[2][1]+=a.z*v.y; acc[2][2]+=a.z*v.z; acc[2][3]+=a.z*v.w;
      acc[3][0]+=a.w*v.x; acc[3][1]+=a.w*v.y; acc[3][2]+=a.w*v.z; acc[3][3]+=a.w*v.w;
    }
  }
  float* pb = part + (size_t)mc * 524288;
  #pragma unroll
  for (int i = 0; i < 4; ++i) {
    const int n = n0 + ty*4 + i;
    float4 o = make_float4(acc[i][0], acc[i][1], acc[i][2], acc[i][3]);
    *(float4*)&pb[((size_t)(b*256 + n))*256 + h*32 + tx*4] = o;
  }
}

// Sum the 8 m-chunk partials -> aout. 131072 float4 elements, grid 512.
__global__ __launch_bounds__(256) void pv_reduce(
    const float* __restrict__ part, float* __restrict__ outp) {
  const int idx = blockIdx.x * 256 + threadIdx.x;
  const float4* p = (const float4*)part;
  float4 s = p[idx];
  #pragma unroll
  for (int c = 1; c < 8; ++c) {
    float4 t = p[idx + c*131072];
    s.x += t.x; s.y += t.y; s.z += t.z; s.w += t.w;
  }
  ((float4*)outp)[idx] = s;
}

} // namespace

extern "C" void kernel_launch(void* const* d_in, const int* in_sizes, int n_in,
                              void* d_out, int out_size, void* d_ws, size_t ws_size,
                              hipStream_t stream) {
  (void)in_sizes; (void)n_in; (void)out_size; (void)ws_size;
  const float* latents = (const float*)d_in[0];
  const float* context = (const float*)d_in[1];
  const float* q_w    = (const float*)d_in[2];
  const float* k_w    = (const float*)d_in[3];
  const float* f_w    = (const float*)d_in[4];
  const float* f_b    = (const float*)d_in[5];
  const float* h_w    = (const float*)d_in[6];
  const float* h_b    = (const float*)d_in[7];
  const float* fk0    = (const float*)d_in[8];
  const float* fk1    = (const float*)d_in[9];
  const float* fk2    = (const float*)d_in[10];
  const float* proj_w = (const float*)d_in[11];
  const float* proj_b = (const float*)d_in[12];

  float* out0 = (float*)d_out;                  // (8,256,256)
  float* attn = out0 + (size_t)8*256*256;       // (8,8,256,4096)

  // workspace layout (floats)
  float* w    = (float*)d_ws;
  float* qb    = w;                       // 524288
  float* kTb   = qb   + 524288;           // 8388608  (transposed K: [b][c][m])
  float* buf1  = kTb  + 8388608;          // 8388608  (f out / conv; later PV partials)
  float* buf2  = buf1 + 8388608;          // 8388608
  float* gates = buf2 + 8388608;          // 131072
  float* vall  = gates + 131072;          // 8388608
  float* aout  = vall + 8388608;          // 524288
  float* vlin  = buf2;                    // alias: buf2 dead after conv5
  float* part  = buf1;                    // alias: buf1 dead after dwconv7 (16 MB used)

  gemm_xwt<<<dim3(32, 4),  256, 0, stream>>>(latents, q_w, nullptr, qb, 256);
  gemm_kt <<<dim3(512, 4), 256, 0, stream>>>(context, k_w, kTb);
  gemm_f  <<<dim3(512, 5), 256, 0, stream>>>(context, f_w, f_b, buf1, gates);
  dwconv<3, 0, true ><<<2048, 256, 0, stream>>>(buf1, fk0, gates, buf2, vall);
  dwconv<5, 1, false><<<2048, 256, 0, stream>>>(buf2, fk1, gates, buf1, vall);
  dwconv7            <<<2048, 256, 0, stream>>>(buf1, fk2, gates, vall);
  gemm_h  <<<dim3(64, 4, 8), 256, 0, stream>>>(vall, h_w, h_b, vlin);
  attn_softmax2<<<2048, 256, 0, stream>>>(qb, kTb, attn);
  pv_split<<<dim3(2, 64, 8), 256, 0, stream>>>(attn, vlin, part);
  pv_reduce<<<512, 256, 0, stream>>>(part, aout);
  gemm_xwt<<<dim3(32, 4), 256, 0, stream>>>(aout, proj_w, proj_b, out0, 256);
}

// Round 5
// 635.335 us; speedup vs baseline: 1.8504x; 1.0462x over previous
//
#include <hip/hip_runtime.h>
#include <math.h>

// Shapes: B=8, N_L=256, C=256, NH=8, HD=32, H=W=64, N_C=4096, L=3, KS={3,5,7}
// Reference reshape semantics: v[b][m][dim] with m = c*16 + (hw>>8), dim = hw&255.

namespace {

constexpr float CSCALE = 0.17677669529663688f;

typedef __attribute__((ext_vector_type(8))) __bf16 bf16x8;
typedef __attribute__((ext_vector_type(4))) float f32x4;

__device__ __forceinline__ float gelu_f(float x) {
  return 0.5f * x * (1.0f + erff(x * 0.70710678118654752f));
}

__device__ __forceinline__ unsigned short f2bf(float f) {
  union { float f; unsigned u; } v; v.f = f;
  unsigned r = v.u + 0x7fffu + ((v.u >> 16) & 1u);  // RNE
  return (unsigned short)(r >> 16);
}

// ---------------------------------------------------------------------------
// Generic fp32 GEMM: out[r][n] = X[r][:] . W[n][:] + bias[n]  (K=256, N=256)
// ---------------------------------------------------------------------------
__global__ __launch_bounds__(256) void gemm_xwt(
    const float* __restrict__ X, const float* __restrict__ W,
    const float* __restrict__ bias, float* __restrict__ out, int N) {
  __shared__ float As[64][33];
  __shared__ float Bs[64][33];
  const int tid = threadIdx.x;
  const int r0 = blockIdx.x * 64, n0 = blockIdx.y * 64;
  const int row = tid & 63, kq = (tid >> 6) * 8;
  const int ty = tid >> 4, tx = tid & 15;
  float acc[4][4] = {};
  for (int k0 = 0; k0 < 256; k0 += 32) {
    const float4* xp = (const float4*)(X + (size_t)(r0 + row) * 256 + k0 + kq);
    float4 a0 = xp[0], a1 = xp[1];
    const float4* wp = (const float4*)(W + (size_t)(n0 + row) * 256 + k0 + kq);
    float4 b0 = wp[0], b1 = wp[1];
    As[row][kq+0]=a0.x; As[row][kq+1]=a0.y; As[row][kq+2]=a0.z; As[row][kq+3]=a0.w;
    As[row][kq+4]=a1.x; As[row][kq+5]=a1.y; As[row][kq+6]=a1.z; As[row][kq+7]=a1.w;
    Bs[row][kq+0]=b0.x; Bs[row][kq+1]=b0.y; Bs[row][kq+2]=b0.z; Bs[row][kq+3]=b0.w;
    Bs[row][kq+4]=b1.x; Bs[row][kq+5]=b1.y; Bs[row][kq+6]=b1.z; Bs[row][kq+7]=b1.w;
    __syncthreads();
    #pragma unroll
    for (int k = 0; k < 32; ++k) {
      float a[4], bv[4];
      #pragma unroll
      for (int i = 0; i < 4; ++i) a[i] = As[ty*4+i][k];
      #pragma unroll
      for (int j = 0; j < 4; ++j) bv[j] = Bs[tx*4+j][k];
      #pragma unroll
      for (int i = 0; i < 4; ++i)
        #pragma unroll
        for (int j = 0; j < 4; ++j) acc[i][j] += a[i] * bv[j];
    }
    __syncthreads();
  }
  #pragma unroll
  for (int j = 0; j < 4; ++j) {
    const int n = n0 + tx*4 + j;
    const float bb = bias ? bias[n] : 0.0f;
    #pragma unroll
    for (int i = 0; i < 4; ++i)
      out[(size_t)(r0 + ty*4 + i) * N + n] = acc[i][j] + bb;
  }
}

// ---------------------------------------------------------------------------
// Same GEMM but bf16 output (no bias), N=256. For q/k projections.
// ---------------------------------------------------------------------------
__global__ __launch_bounds__(256) void gemm_xwt_bf16(
    const float* __restrict__ X, const float* __restrict__ W,
    unsigned short* __restrict__ out) {
  __shared__ float As[64][33];
  __shared__ float Bs[64][33];
  const int tid = threadIdx.x;
  const int r0 = blockIdx.x * 64, n0 = blockIdx.y * 64;
  const int row = tid & 63, kq = (tid >> 6) * 8;
  const int ty = tid >> 4, tx = tid & 15;
  float acc[4][4] = {};
  for (int k0 = 0; k0 < 256; k0 += 32) {
    const float4* xp = (const float4*)(X + (size_t)(r0 + row) * 256 + k0 + kq);
    float4 a0 = xp[0], a1 = xp[1];
    const float4* wp = (const float4*)(W + (size_t)(n0 + row) * 256 + k0 + kq);
    float4 b0 = wp[0], b1 = wp[1];
    As[row][kq+0]=a0.x; As[row][kq+1]=a0.y; As[row][kq+2]=a0.z; As[row][kq+3]=a0.w;
    As[row][kq+4]=a1.x; As[row][kq+5]=a1.y; As[row][kq+6]=a1.z; As[row][kq+7]=a1.w;
    Bs[row][kq+0]=b0.x; Bs[row][kq+1]=b0.y; Bs[row][kq+2]=b0.z; Bs[row][kq+3]=b0.w;
    Bs[row][kq+4]=b1.x; Bs[row][kq+5]=b1.y; Bs[row][kq+6]=b1.z; Bs[row][kq+7]=b1.w;
    __syncthreads();
    #pragma unroll
    for (int k = 0; k < 32; ++k) {
      float a[4], bv[4];
      #pragma unroll
      for (int i = 0; i < 4; ++i) a[i] = As[ty*4+i][k];
      #pragma unroll
      for (int j = 0; j < 4; ++j) bv[j] = Bs[tx*4+j][k];
      #pragma unroll
      for (int i = 0; i < 4; ++i)
        #pragma unroll
        for (int j = 0; j < 4; ++j) acc[i][j] += a[i] * bv[j];
    }
    __syncthreads();
  }
  #pragma unroll
  for (int i = 0; i < 4; ++i) {
    ushort4 o;
    o.x = f2bf(acc[i][0]); o.y = f2bf(acc[i][1]);
    o.z = f2bf(acc[i][2]); o.w = f2bf(acc[i][3]);
    *(ushort4*)&out[(size_t)(r0 + ty*4 + i) * 256 + n0 + tx*4] = o;
  }
}

// ---------------------------------------------------------------------------
// f-projection: scatter n<256 -> vctx[b][n][hw] planar, n>=256 -> gates
// ---------------------------------------------------------------------------
__global__ __launch_bounds__(256) void gemm_f(
    const float* __restrict__ ctx, const float* __restrict__ fw,
    const float* __restrict__ fb, float* __restrict__ vctx,
    float* __restrict__ gates) {
  __shared__ float As[64][33];
  __shared__ float Bs[64][33];
  const int tid = threadIdx.x;
  const int r0 = blockIdx.x * 64, n0 = blockIdx.y * 64;
  const int row = tid & 63, kq = (tid >> 6) * 8;
  const int ty = tid >> 4, tx = tid & 15;
  float acc[4][4] = {};
  for (int k0 = 0; k0 < 256; k0 += 32) {
    const float4* xp = (const float4*)(ctx + (size_t)(r0 + row) * 256 + k0 + kq);
    float4 a0 = xp[0], a1 = xp[1];
    float4 b0 = make_float4(0.f,0.f,0.f,0.f), b1 = b0;
    if (n0 + row < 260) {
      const float4* wp = (const float4*)(fw + (size_t)(n0 + row) * 256 + k0 + kq);
      b0 = wp[0]; b1 = wp[1];
    }
    As[row][kq+0]=a0.x; As[row][kq+1]=a0.y; As[row][kq+2]=a0.z; As[row][kq+3]=a0.w;
    As[row][kq+4]=a1.x; As[row][kq+5]=a1.y; As[row][kq+6]=a1.z; As[row][kq+7]=a1.w;
    Bs[row][kq+0]=b0.x; Bs[row][kq+1]=b0.y; Bs[row][kq+2]=b0.z; Bs[row][kq+3]=b0.w;
    Bs[row][kq+4]=b1.x; Bs[row][kq+5]=b1.y; Bs[row][kq+6]=b1.z; Bs[row][kq+7]=b1.w;
    __syncthreads();
    #pragma unroll
    for (int k = 0; k < 32; ++k) {
      float a[4], bv[4];
      #pragma unroll
      for (int i = 0; i < 4; ++i) a[i] = As[ty*4+i][k];
      #pragma unroll
      for (int j = 0; j < 4; ++j) bv[j] = Bs[tx*4+j][k];
      #pragma unroll
      for (int i = 0; i < 4; ++i)
        #pragma unroll
        for (int j = 0; j < 4; ++j) acc[i][j] += a[i] * bv[j];
    }
    __syncthreads();
  }
  #pragma unroll
  for (int j = 0; j < 4; ++j) {
    const int n = n0 + tx*4 + j;
    if (n >= 260) continue;
    const float bb = fb[n];
    #pragma unroll
    for (int i = 0; i < 4; ++i) {
      const int r = r0 + ty*4 + i;
      const int b = r >> 12, hw = r & 4095;
      const float v = acc[i][j] + bb;
      if (n < 256) vctx[((size_t)(b*256 + n)) * 4096 + hw] = v;
      else         gates[((size_t)(b*4 + (n - 256))) * 4096 + hw] = v;
    }
  }
}

// ---------------------------------------------------------------------------
// Depthwise conv + GELU, one (b,c) 64x64 plane per block. grid = 2048
// ---------------------------------------------------------------------------
template<int KK, int LYR, bool FIRST>
__global__ __launch_bounds__(256) void dwconv(
    const float* __restrict__ in, const float* __restrict__ wk,
    const float* __restrict__ gates, float* __restrict__ outv,
    float* __restrict__ vall) {
  constexpr int P = KK / 2, TW = 64 + 2 * P;
  __shared__ float tile[TW * TW];
  __shared__ float wsh[KK * KK];
  const int tid = threadIdx.x;
  const int b = blockIdx.x >> 8, c = blockIdx.x & 255;
  const float* ip = in + (size_t)(b*256 + c) * 4096;
  if (tid < KK*KK) wsh[tid] = wk[c*KK*KK + tid];
  for (int idx = tid; idx < TW*TW; idx += 256) {
    const int ty = idx / TW, tx = idx - ty*TW;
    const int gy = ty - P, gx = tx - P;
    tile[idx] = (gy >= 0 && gy < 64 && gx >= 0 && gx < 64) ? ip[gy*64 + gx] : 0.0f;
  }
  __syncthreads();
  const float* gl = gates + (size_t)(b*4 + LYR) * 4096;
  float* vp = vall + (size_t)(b*256 + c) * 4096;
  float* op = outv + (size_t)(b*256 + c) * 4096;
  #pragma unroll
  for (int ii = 0; ii < 16; ++ii) {
    const int pix = ii*256 + tid;
    const int y = pix >> 6, x = pix & 63;
    float acc = 0.f;
    #pragma unroll
    for (int ky = 0; ky < KK; ++ky)
      #pragma unroll
      for (int kx = 0; kx < KK; ++kx)
        acc += wsh[ky*KK + kx] * tile[(y+ky)*TW + (x+kx)];
    const float g = gelu_f(acc);
    op[pix] = g;
    const float t = g * gl[pix];
    if (FIRST) vp[pix] = t; else vp[pix] += t;
  }
}

// Last conv (k=7, layer 2) + global-mean term.
__global__ __launch_bounds__(256) void dwconv7(
    const float* __restrict__ in, const float* __restrict__ wk,
    const float* __restrict__ gates, float* __restrict__ vall) {
  constexpr int KK = 7, P = 3, TW = 70;
  __shared__ float tile[TW * TW];
  __shared__ float wsh[KK * KK];
  __shared__ float red[4];
  const int tid = threadIdx.x;
  const int b = blockIdx.x >> 8, c = blockIdx.x & 255;
  const float* ip = in + (size_t)(b*256 + c) * 4096;
  if (tid < KK*KK) wsh[tid] = wk[c*KK*KK + tid];
  for (int idx = tid; idx < TW*TW; idx += 256) {
    const int ty = idx / TW, tx = idx - ty*TW;
    const int gy = ty - P, gx = tx - P;
    tile[idx] = (gy >= 0 && gy < 64 && gx >= 0 && gx < 64) ? ip[gy*64 + gx] : 0.0f;
  }
  __syncthreads();
  float gv[16];
  #pragma unroll
  for (int ii = 0; ii < 16; ++ii) {
    const int pix = ii*256 + tid;
    const int y = pix >> 6, x = pix & 63;
    float acc = 0.f;
    #pragma unroll
    for (int ky = 0; ky < KK; ++ky)
      #pragma unroll
      for (int kx = 0; kx < KK; ++kx)
        acc += wsh[ky*KK + kx] * tile[(y+ky)*TW + (x+kx)];
    gv[ii] = gelu_f(acc);
  }
  float s = 0.f;
  #pragma unroll
  for (int ii = 0; ii < 16; ++ii) s += gv[ii];
  #pragma unroll
  for (int off = 32; off >= 1; off >>= 1) s += __shfl_xor(s, off, 64);
  if ((tid & 63) == 0) red[tid >> 6] = s;
  __syncthreads();
  const float vg = gelu_f((red[0]+red[1]+red[2]+red[3]) * (1.0f/4096.0f));
  const float* g2 = gates + (size_t)(b*4 + 2) * 4096;
  const float* g3 = gates + (size_t)(b*4 + 3) * 4096;
  float* vp = vall + (size_t)(b*256 + c) * 4096;
  #pragma unroll
  for (int ii = 0; ii < 16; ++ii) {
    const int pix = ii*256 + tid;
    vp[pix] += gv[ii]*g2[pix] + vg*g3[pix];
  }
}

// ---------------------------------------------------------------------------
// h-GEMM (fp32, VERIFIED in rounds 1-3): v_mod[b,d,hw] = sum_c h_w[d,c]*
// v_all[b,c,hw] + h_b[d]; written permuted: vlin[b][m = d*16+hw/256][hw%256]
// ---------------------------------------------------------------------------
__global__ __launch_bounds__(256) void gemm_h(
    const float* __restrict__ vall, const float* __restrict__ hwm,
    const float* __restrict__ hb, float* __restrict__ vlin) {
  __shared__ float As[32][65];   // [c][hw]
  __shared__ float Bs[64][33];   // [d][c]
  const int tid = threadIdx.x;
  const int hw0 = blockIdx.x * 64, d0 = blockIdx.y * 64, b = blockIdx.z;
  const int ty = tid >> 4, tx = tid & 15;
  float acc[4][4] = {};
  for (int c0 = 0; c0 < 256; c0 += 32) {
    const int cc = tid >> 3, hwi = (tid & 7) * 8;
    const float4* vp = (const float4*)(vall + (size_t)(b*256 + c0 + cc)*4096 + hw0 + hwi);
    float4 a0 = vp[0], a1 = vp[1];
    As[cc][hwi+0]=a0.x; As[cc][hwi+1]=a0.y; As[cc][hwi+2]=a0.z; As[cc][hwi+3]=a0.w;
    As[cc][hwi+4]=a1.x; As[cc][hwi+5]=a1.y; As[cc][hwi+6]=a1.z; As[cc][hwi+7]=a1.w;
    const int dd = tid & 63, cq = (tid >> 6) * 8;
    const float4* wp = (const float4*)(hwm + (size_t)(d0 + dd)*256 + c0 + cq);
    float4 b0 = wp[0], b1 = wp[1];
    Bs[dd][cq+0]=b0.x; Bs[dd][cq+1]=b0.y; Bs[dd][cq+2]=b0.z; Bs[dd][cq+3]=b0.w;
    Bs[dd][cq+4]=b1.x; Bs[dd][cq+5]=b1.y; Bs[dd][cq+6]=b1.z; Bs[dd][cq+7]=b1.w;
    __syncthreads();
    #pragma unroll
    for (int k = 0; k < 32; ++k) {
      float a[4], bv[4];
      #pragma unroll
      for (int i = 0; i < 4; ++i) a[i] = As[k][ty*4+i];
      #pragma unroll
      for (int j = 0; j < 4; ++j) bv[j] = Bs[tx*4+j][k];
      #pragma unroll
      for (int i = 0; i < 4; ++i)
        #pragma unroll
        for (int j = 0; j < 4; ++j) acc[i][j] += a[i] * bv[j];
    }
    __syncthreads();
  }
  #pragma unroll
  for (int j = 0; j < 4; ++j) {
    const int d = d0 + tx*4 + j;
    const float bb = hb[d];
    #pragma unroll
    for (int i = 0; i < 4; ++i) {
      const int hw = hw0 + ty*4 + i;
      const int m = d*16 + (hw >> 8);
      vlin[((size_t)b*4096 + m)*256 + (hw & 255)] = acc[i][j] + bb;
    }
  }
}

// ---------------------------------------------------------------------------
// Transpose+convert: vT[b][dim][m] (bf16) from vlin[b][m][dim] (fp32).
// 64x64 tiles; grid = (64 m-tiles, 4 dim-tiles, 8 b).
// ---------------------------------------------------------------------------
__global__ __launch_bounds__(256) void vtrans(
    const float* __restrict__ vlin, unsigned short* __restrict__ vT) {
  __shared__ float T[64][65];
  const int tid = threadIdx.x;
  const int m0 = blockIdx.x * 64, d0 = blockIdx.y * 64, b = blockIdx.z;
  const int r = tid >> 2, ck = (tid & 3) * 16;
  const float4* src = (const float4*)(vlin + ((size_t)(b*4096 + m0 + r))*256 + d0 + ck);
  float4 v0 = src[0], v1 = src[1], v2 = src[2], v3 = src[3];
  T[r][ck+ 0]=v0.x; T[r][ck+ 1]=v0.y; T[r][ck+ 2]=v0.z; T[r][ck+ 3]=v0.w;
  T[r][ck+ 4]=v1.x; T[r][ck+ 5]=v1.y; T[r][ck+ 6]=v1.z; T[r][ck+ 7]=v1.w;
  T[r][ck+ 8]=v2.x; T[r][ck+ 9]=v2.y; T[r][ck+10]=v2.z; T[r][ck+11]=v2.w;
  T[r][ck+12]=v3.x; T[r][ck+13]=v3.y; T[r][ck+14]=v3.z; T[r][ck+15]=v3.w;
  __syncthreads();
  const int dd = tid >> 2, mk = (tid & 3) * 16;
  ushort4 o[4];
  #pragma unroll
  for (int q = 0; q < 4; ++q) {
    o[q].x = f2bf(T[mk + q*4 + 0][dd]);
    o[q].y = f2bf(T[mk + q*4 + 1][dd]);
    o[q].z = f2bf(T[mk + q*4 + 2][dd]);
    o[q].w = f2bf(T[mk + q*4 + 3][dd]);
  }
  ushort4* dst = (ushort4*)&vT[((size_t)(b*256 + d0 + dd))*4096 + m0 + mk];
  dst[0] = o[0]; dst[1] = o[1]; dst[2] = o[2]; dst[3] = o[3];
}

// ---------------------------------------------------------------------------
// Attention with bf16 MFMA. Block = (bh, 16-row n-tile), 4 waves each own an
// m-quarter (1024). Two passes: rowsum, then scale+store. No max-sub (|logit|
// small). D layout: col=lane&15 (m), row=(lane>>4)*4+reg (n).
// grid = 1024 (bh = blk & 63 for XCD locality of the K slice).
// ---------------------------------------------------------------------------
__global__ __launch_bounds__(256) void attn_mfma(
    const unsigned short* __restrict__ qb, const unsigned short* __restrict__ kb,
    float* __restrict__ attn) {
  const int blk = blockIdx.x;
  const int bh = blk & 63, nt = blk >> 6;
  const int b = bh >> 3, h = bh & 7;
  const int tid = threadIdx.x;
  const int w = tid >> 6, l = tid & 63;
  const int lr = l & 15, lk = l >> 4;
  const int n0 = nt * 16;
  __shared__ float rs[4][16];
  bf16x8 aq = *reinterpret_cast<const bf16x8*>(
      qb + ((size_t)(b*256 + n0 + lr))*256 + h*32 + lk*8);
  const unsigned short* kbase = kb + (size_t)b*4096*256 + h*32 + lk*8;
  float sum[4] = {0.f, 0.f, 0.f, 0.f};
  #pragma unroll 2
  for (int mt = 0; mt < 64; ++mt) {
    const int m0 = w*1024 + mt*16;
    bf16x8 bk = *reinterpret_cast<const bf16x8*>(kbase + (size_t)(m0 + lr)*256);
    f32x4 d = __builtin_amdgcn_mfma_f32_16x16x32_bf16(aq, bk, (f32x4){0.f,0.f,0.f,0.f}, 0, 0, 0);
    #pragma unroll
    for (int r = 0; r < 4; ++r) sum[r] += __expf(d[r] * CSCALE);
  }
  #pragma unroll
  for (int r = 0; r < 4; ++r) {
    #pragma unroll
    for (int m = 1; m < 16; m <<= 1) sum[r] += __shfl_xor(sum[r], m, 64);
  }
  if (lr == 0) {
    #pragma unroll
    for (int r = 0; r < 4; ++r) rs[w][lk*4 + r] = sum[r];
  }
  __syncthreads();
  float invS[4];
  #pragma unroll
  for (int r = 0; r < 4; ++r) {
    const int rowi = lk*4 + r;
    invS[r] = 1.0f / (rs[0][rowi] + rs[1][rowi] + rs[2][rowi] + rs[3][rowi]);
  }
  float* ab = attn + ((size_t)bh*256 + n0) * 4096;
  #pragma unroll 2
  for (int mt = 0; mt < 64; ++mt) {
    const int m0 = w*1024 + mt*16;
    bf16x8 bk = *reinterpret_cast<const bf16x8*>(kbase + (size_t)(m0 + lr)*256);
    f32x4 d = __builtin_amdgcn_mfma_f32_16x16x32_bf16(aq, bk, (f32x4){0.f,0.f,0.f,0.f}, 0, 0, 0);
    #pragma unroll
    for (int r = 0; r < 4; ++r)
      ab[(size_t)(lk*4 + r)*4096 + m0 + lr] = __expf(d[r] * CSCALE) * invS[r];
  }
}

// ---------------------------------------------------------------------------
// PV with bf16 MFMA: out[n][d] = sum_m p[n][m] * V[m][d], V from vT[b][dim][m].
// Block = (bh, 16-row n-tile); 4 waves split m (quarters); LDS reduce.
// ---------------------------------------------------------------------------
__global__ __launch_bounds__(256) void pv_mfma(
    const float* __restrict__ attn, const unsigned short* __restrict__ vt,
    float* __restrict__ outs) {
  const int blk = blockIdx.x;
  const int bh = blk & 63, nt = blk >> 6;
  const int b = bh >> 3, h = bh & 7;
  const int tid = threadIdx.x;
  const int w = tid >> 6, l = tid & 63;
  const int lr = l & 15, lk = l >> 4;
  const int n0 = nt * 16;
  __shared__ float osum[4][16][32];
  const float* ap = attn + ((size_t)bh*256 + n0 + lr)*4096 + lk*8;
  const unsigned short* v0p = vt + ((size_t)(b*256 + h*32 + lr))*4096 + lk*8;
  const unsigned short* v1p = v0p + (size_t)16*4096;
  f32x4 acc0 = {0.f,0.f,0.f,0.f}, acc1 = {0.f,0.f,0.f,0.f};
  #pragma unroll 4
  for (int mt = 0; mt < 32; ++mt) {
    const int m0 = w*1024 + mt*32;
    float4 pa0 = *(const float4*)(ap + m0);
    float4 pa1 = *(const float4*)(ap + m0 + 4);
    bf16x8 bv0 = *reinterpret_cast<const bf16x8*>(v0p + m0);
    bf16x8 bv1 = *reinterpret_cast<const bf16x8*>(v1p + m0);
    union { unsigned short u[8]; bf16x8 v; } A;
    A.u[0] = f2bf(pa0.x); A.u[1] = f2bf(pa0.y); A.u[2] = f2bf(pa0.z); A.u[3] = f2bf(pa0.w);
    A.u[4] = f2bf(pa1.x); A.u[5] = f2bf(pa1.y); A.u[6] = f2bf(pa1.z); A.u[7] = f2bf(pa1.w);
    acc0 = __builtin_amdgcn_mfma_f32_16x16x32_bf16(A.v, bv0, acc0, 0, 0, 0);
    acc1 = __builtin_amdgcn_mfma_f32_16x16x32_bf16(A.v, bv1, acc1, 0, 0, 0);
  }
  #pragma unroll
  for (int r = 0; r < 4; ++r) {
    osum[w][lk*4 + r][lr]      = acc0[r];
    osum[w][lk*4 + r][16 + lr] = acc1[r];
  }
  __syncthreads();
  for (int i = tid; i < 512; i += 256) {
    const int n = i >> 5, d = i & 31;
    const float s = osum[0][n][d] + osum[1][n][d] + osum[2][n][d] + osum[3][n][d];
    outs[((size_t)(b*256 + n0 + n))*256 + h*32 + d] = s;
  }
}

} // namespace

extern "C" void kernel_launch(void* const* d_in, const int* in_sizes, int n_in,
                              void* d_out, int out_size, void* d_ws, size_t ws_size,
                              hipStream_t stream) {
  (void)in_sizes; (void)n_in; (void)out_size; (void)ws_size;
  const float* latents = (const float*)d_in[0];
  const float* context = (const float*)d_in[1];
  const float* q_w    = (const float*)d_in[2];
  const float* k_w    = (const float*)d_in[3];
  const float* f_w    = (const float*)d_in[4];
  const float* f_b    = (const float*)d_in[5];
  const float* h_w    = (const float*)d_in[6];
  const float* h_b    = (const float*)d_in[7];
  const float* fk0    = (const float*)d_in[8];
  const float* fk1    = (const float*)d_in[9];
  const float* fk2    = (const float*)d_in[10];
  const float* proj_w = (const float*)d_in[11];
  const float* proj_b = (const float*)d_in[12];

  float* out0 = (float*)d_out;                  // (8,256,256)
  float* attn = out0 + (size_t)8*256*256;       // (8,8,256,4096)

  // workspace layout (byte offsets)
  char* w = (char*)d_ws;
  unsigned short* q_bf = (unsigned short*)(w + 0x0);        //  1 MB  (8,256,256) bf16
  unsigned short* k_bf = (unsigned short*)(w + 0x100000);   // 16 MB  (8,4096,256) bf16
  unsigned short* v_tb = (unsigned short*)(w + 0x1100000);  // 16 MB  (8,256,4096) bf16 vT[dim][m]
  float* buf1  = (float*)(w + 0x2100000);                   // 32 MB
  float* buf2  = (float*)(w + 0x4100000);                   // 32 MB (later vlin)
  float* gates = (float*)(w + 0x6100000);                   // 0.5 MB
  float* vall  = (float*)(w + 0x6180000);                   // 32 MB
  float* aout  = (float*)(w + 0x8180000);                   //  2 MB
  float* vlin  = buf2;                                      // alias: buf2 dead after conv5

  gemm_xwt_bf16<<<dim3(32, 4),  256, 0, stream>>>(latents, q_w, q_bf);
  gemm_xwt_bf16<<<dim3(512, 4), 256, 0, stream>>>(context, k_w, k_bf);
  gemm_f  <<<dim3(512, 5), 256, 0, stream>>>(context, f_w, f_b, buf1, gates);
  dwconv<3, 0, true ><<<2048, 256, 0, stream>>>(buf1, fk0, gates, buf2, vall);
  dwconv<5, 1, false><<<2048, 256, 0, stream>>>(buf2, fk1, gates, buf1, vall);
  dwconv7            <<<2048, 256, 0, stream>>>(buf1, fk2, gates, vall);
  gemm_h  <<<dim3(64, 4, 8), 256, 0, stream>>>(vall, h_w, h_b, vlin);
  vtrans  <<<dim3(64, 4, 8), 256, 0, stream>>>(vlin, v_tb);
  attn_mfma<<<1024, 256, 0, stream>>>(q_bf, k_bf, attn);
  pv_mfma  <<<1024, 256, 0, stream>>>(attn, v_tb, aout);
  gemm_xwt<<<dim3(32, 4), 256, 0, stream>>>(aout, proj_w, proj_b, out0, 256);
}

// Round 6
// 558.987 us; speedup vs baseline: 2.1031x; 1.1366x over previous
//
#include <hip/hip_runtime.h>
#include <math.h>

// Shapes: B=8, N_L=256, C=256, NH=8, HD=32, H=W=64, N_C=4096, L=3, KS={3,5,7}
// Reference reshape semantics: v[b][m][dim] with m = c*16 + (hw>>8), dim = hw&255.

namespace {

constexpr float CSCALE = 0.17677669529663688f;

typedef __attribute__((ext_vector_type(8))) __bf16 bf16x8;
typedef __attribute__((ext_vector_type(4))) float f32x4;

__device__ __forceinline__ float gelu_f(float x) {
  return 0.5f * x * (1.0f + erff(x * 0.70710678118654752f));
}

__device__ __forceinline__ unsigned short f2bf(float f) {
  union { float f; unsigned u; } v; v.f = f;
  unsigned r = v.u + 0x7fffu + ((v.u >> 16) & 1u);  // RNE
  return (unsigned short)(r >> 16);
}

// ---------------------------------------------------------------------------
// Generic fp32 GEMM: out[r][n] = X[r][:] . W[n][:] + bias[n]  (K=256, N=256)
// ---------------------------------------------------------------------------
__global__ __launch_bounds__(256) void gemm_xwt(
    const float* __restrict__ X, const float* __restrict__ W,
    const float* __restrict__ bias, float* __restrict__ out, int N) {
  __shared__ float As[64][33];
  __shared__ float Bs[64][33];
  const int tid = threadIdx.x;
  const int r0 = blockIdx.x * 64, n0 = blockIdx.y * 64;
  const int row = tid & 63, kq = (tid >> 6) * 8;
  const int ty = tid >> 4, tx = tid & 15;
  float acc[4][4] = {};
  for (int k0 = 0; k0 < 256; k0 += 32) {
    const float4* xp = (const float4*)(X + (size_t)(r0 + row) * 256 + k0 + kq);
    float4 a0 = xp[0], a1 = xp[1];
    const float4* wp = (const float4*)(W + (size_t)(n0 + row) * 256 + k0 + kq);
    float4 b0 = wp[0], b1 = wp[1];
    As[row][kq+0]=a0.x; As[row][kq+1]=a0.y; As[row][kq+2]=a0.z; As[row][kq+3]=a0.w;
    As[row][kq+4]=a1.x; As[row][kq+5]=a1.y; As[row][kq+6]=a1.z; As[row][kq+7]=a1.w;
    Bs[row][kq+0]=b0.x; Bs[row][kq+1]=b0.y; Bs[row][kq+2]=b0.z; Bs[row][kq+3]=b0.w;
    Bs[row][kq+4]=b1.x; Bs[row][kq+5]=b1.y; Bs[row][kq+6]=b1.z; Bs[row][kq+7]=b1.w;
    __syncthreads();
    #pragma unroll
    for (int k = 0; k < 32; ++k) {
      float a[4], bv[4];
      #pragma unroll
      for (int i = 0; i < 4; ++i) a[i] = As[ty*4+i][k];
      #pragma unroll
      for (int j = 0; j < 4; ++j) bv[j] = Bs[tx*4+j][k];
      #pragma unroll
      for (int i = 0; i < 4; ++i)
        #pragma unroll
        for (int j = 0; j < 4; ++j) acc[i][j] += a[i] * bv[j];
    }
    __syncthreads();
  }
  #pragma unroll
  for (int j = 0; j < 4; ++j) {
    const int n = n0 + tx*4 + j;
    const float bb = bias ? bias[n] : 0.0f;
    #pragma unroll
    for (int i = 0; i < 4; ++i)
      out[(size_t)(r0 + ty*4 + i) * N + n] = acc[i][j] + bb;
  }
}

// ---------------------------------------------------------------------------
// Same GEMM but bf16 output (no bias), N=256. For q/k projections.
// ---------------------------------------------------------------------------
__global__ __launch_bounds__(256) void gemm_xwt_bf16(
    const float* __restrict__ X, const float* __restrict__ W,
    unsigned short* __restrict__ out) {
  __shared__ float As[64][33];
  __shared__ float Bs[64][33];
  const int tid = threadIdx.x;
  const int r0 = blockIdx.x * 64, n0 = blockIdx.y * 64;
  const int row = tid & 63, kq = (tid >> 6) * 8;
  const int ty = tid >> 4, tx = tid & 15;
  float acc[4][4] = {};
  for (int k0 = 0; k0 < 256; k0 += 32) {
    const float4* xp = (const float4*)(X + (size_t)(r0 + row) * 256 + k0 + kq);
    float4 a0 = xp[0], a1 = xp[1];
    const float4* wp = (const float4*)(W + (size_t)(n0 + row) * 256 + k0 + kq);
    float4 b0 = wp[0], b1 = wp[1];
    As[row][kq+0]=a0.x; As[row][kq+1]=a0.y; As[row][kq+2]=a0.z; As[row][kq+3]=a0.w;
    As[row][kq+4]=a1.x; As[row][kq+5]=a1.y; As[row][kq+6]=a1.z; As[row][kq+7]=a1.w;
    Bs[row][kq+0]=b0.x; Bs[row][kq+1]=b0.y; Bs[row][kq+2]=b0.z; Bs[row][kq+3]=b0.w;
    Bs[row][kq+4]=b1.x; Bs[row][kq+5]=b1.y; Bs[row][kq+6]=b1.z; Bs[row][kq+7]=b1.w;
    __syncthreads();
    #pragma unroll
    for (int k = 0; k < 32; ++k) {
      float a[4], bv[4];
      #pragma unroll
      for (int i = 0; i < 4; ++i) a[i] = As[ty*4+i][k];
      #pragma unroll
      for (int j = 0; j < 4; ++j) bv[j] = Bs[tx*4+j][k];
      #pragma unroll
      for (int i = 0; i < 4; ++i)
        #pragma unroll
        for (int j = 0; j < 4; ++j) acc[i][j] += a[i] * bv[j];
    }
    __syncthreads();
  }
  #pragma unroll
  for (int i = 0; i < 4; ++i) {
    ushort4 o;
    o.x = f2bf(acc[i][0]); o.y = f2bf(acc[i][1]);
    o.z = f2bf(acc[i][2]); o.w = f2bf(acc[i][3]);
    *(ushort4*)&out[(size_t)(r0 + ty*4 + i) * 256 + n0 + tx*4] = o;
  }
}

// ---------------------------------------------------------------------------
// f-projection: scatter n<256 -> vctx[b][n][hw] planar, n>=256 -> gates
// ---------------------------------------------------------------------------
__global__ __launch_bounds__(256) void gemm_f(
    const float* __restrict__ ctx, const float* __restrict__ fw,
    const float* __restrict__ fb, float* __restrict__ vctx,
    float* __restrict__ gates) {
  __shared__ float As[64][33];
  __shared__ float Bs[64][33];
  const int tid = threadIdx.x;
  const int r0 = blockIdx.x * 64, n0 = blockIdx.y * 64;
  const int row = tid & 63, kq = (tid >> 6) * 8;
  const int ty = tid >> 4, tx = tid & 15;
  float acc[4][4] = {};
  for (int k0 = 0; k0 < 256; k0 += 32) {
    const float4* xp = (const float4*)(ctx + (size_t)(r0 + row) * 256 + k0 + kq);
    float4 a0 = xp[0], a1 = xp[1];
    float4 b0 = make_float4(0.f,0.f,0.f,0.f), b1 = b0;
    if (n0 + row < 260) {
      const float4* wp = (const float4*)(fw + (size_t)(n0 + row) * 256 + k0 + kq);
      b0 = wp[0]; b1 = wp[1];
    }
    As[row][kq+0]=a0.x; As[row][kq+1]=a0.y; As[row][kq+2]=a0.z; As[row][kq+3]=a0.w;
    As[row][kq+4]=a1.x; As[row][kq+5]=a1.y; As[row][kq+6]=a1.z; As[row][kq+7]=a1.w;
    Bs[row][kq+0]=b0.x; Bs[row][kq+1]=b0.y; Bs[row][kq+2]=b0.z; Bs[row][kq+3]=b0.w;
    Bs[row][kq+4]=b1.x; Bs[row][kq+5]=b1.y; Bs[row][kq+6]=b1.z; Bs[row][kq+7]=b1.w;
    __syncthreads();
    #pragma unroll
    for (int k = 0; k < 32; ++k) {
      float a[4], bv[4];
      #pragma unroll
      for (int i = 0; i < 4; ++i) a[i] = As[ty*4+i][k];
      #pragma unroll
      for (int j = 0; j < 4; ++j) bv[j] = Bs[tx*4+j][k];
      #pragma unroll
      for (int i = 0; i < 4; ++i)
        #pragma unroll
        for (int j = 0; j < 4; ++j) acc[i][j] += a[i] * bv[j];
    }
    __syncthreads();
  }
  #pragma unroll
  for (int j = 0; j < 4; ++j) {
    const int n = n0 + tx*4 + j;
    if (n >= 260) continue;
    const float bb = fb[n];
    #pragma unroll
    for (int i = 0; i < 4; ++i) {
      const int r = r0 + ty*4 + i;
      const int b = r >> 12, hw = r & 4095;
      const float v = acc[i][j] + bb;
      if (n < 256) vctx[((size_t)(b*256 + n)) * 4096 + hw] = v;
      else         gates[((size_t)(b*4 + (n - 256))) * 4096 + hw] = v;
    }
  }
}

// ---------------------------------------------------------------------------
// FUSED depthwise conv chain: conv3+gelu -> conv5+gelu -> conv7+gelu (+global
// mean term), gated accumulation, one (b,c) 64x64 plane per block. grid=2048.
// Plane lives in a 70x70 zero-framed LDS buffer; interior rewritten per stage.
// ---------------------------------------------------------------------------
__global__ __launch_bounds__(256) void fused_conv(
    const float* __restrict__ in, const float* __restrict__ wk3,
    const float* __restrict__ wk5, const float* __restrict__ wk7,
    const float* __restrict__ gates, float* __restrict__ vall) {
  constexpr int TW = 70;  // 64 + 2*3 frame
  __shared__ float A[TW * TW];
  __shared__ float w3[9];
  __shared__ float w5[25];
  __shared__ float w7[49];
  __shared__ float red[4];
  const int tid = threadIdx.x;
  const int b = blockIdx.x >> 8, c = blockIdx.x & 255;
  if (tid < 9)  w3[tid] = wk3[c*9  + tid];
  else if (tid < 34) w5[tid-9]  = wk5[c*25 + tid-9];
  else if (tid < 83) w7[tid-34] = wk7[c*49 + tid-34];
  const float* ip = in + (size_t)(b*256 + c) * 4096;
  for (int idx = tid; idx < TW*TW; idx += 256) {
    const int ty = idx / TW, tx = idx - ty*TW;
    const int gy = ty - 3, gx = tx - 3;
    A[idx] = (gy >= 0 && gy < 64 && gx >= 0 && gx < 64) ? ip[gy*64 + gx] : 0.0f;
  }
  __syncthreads();
  const float* g0 = gates + (size_t)(b*4 + 0) * 4096;
  const float* g1 = gates + (size_t)(b*4 + 1) * 4096;
  const float* g2 = gates + (size_t)(b*4 + 2) * 4096;
  const float* g3 = gates + (size_t)(b*4 + 3) * 4096;
  float v[16], acc[16];
  // ---- conv3 + gelu ----
  #pragma unroll
  for (int ii = 0; ii < 16; ++ii) {
    const int pix = ii*256 + tid;
    const int y = pix >> 6, x = pix & 63;
    float s = 0.f;
    #pragma unroll
    for (int ky = 0; ky < 3; ++ky)
      #pragma unroll
      for (int kx = 0; kx < 3; ++kx)
        s += w3[ky*3 + kx] * A[(y+2+ky)*TW + (x+2+kx)];
    v[ii] = gelu_f(s);
    acc[ii] = v[ii] * g0[pix];
  }
  __syncthreads();
  #pragma unroll
  for (int ii = 0; ii < 16; ++ii) {
    const int pix = ii*256 + tid;
    A[((pix >> 6) + 3)*TW + (pix & 63) + 3] = v[ii];
  }
  __syncthreads();
  // ---- conv5 + gelu ----
  #pragma unroll
  for (int ii = 0; ii < 16; ++ii) {
    const int pix = ii*256 + tid;
    const int y = pix >> 6, x = pix & 63;
    float s = 0.f;
    #pragma unroll
    for (int ky = 0; ky < 5; ++ky)
      #pragma unroll
      for (int kx = 0; kx < 5; ++kx)
        s += w5[ky*5 + kx] * A[(y+1+ky)*TW + (x+1+kx)];
    v[ii] = gelu_f(s);
    acc[ii] += v[ii] * g1[pix];
  }
  __syncthreads();
  #pragma unroll
  for (int ii = 0; ii < 16; ++ii) {
    const int pix = ii*256 + tid;
    A[((pix >> 6) + 3)*TW + (pix & 63) + 3] = v[ii];
  }
  __syncthreads();
  // ---- conv7 + gelu (+ mean) ----
  float msum = 0.f;
  #pragma unroll
  for (int ii = 0; ii < 16; ++ii) {
    const int pix = ii*256 + tid;
    const int y = pix >> 6, x = pix & 63;
    float s = 0.f;
    #pragma unroll
    for (int ky = 0; ky < 7; ++ky)
      #pragma unroll
      for (int kx = 0; kx < 7; ++kx)
        s += w7[ky*7 + kx] * A[(y+ky)*TW + (x+kx)];
    v[ii] = gelu_f(s);
    acc[ii] += v[ii] * g2[pix];
    msum += v[ii];
  }
  #pragma unroll
  for (int off = 32; off >= 1; off >>= 1) msum += __shfl_xor(msum, off, 64);
  if ((tid & 63) == 0) red[tid >> 6] = msum;
  __syncthreads();
  const float vg = gelu_f((red[0]+red[1]+red[2]+red[3]) * (1.0f/4096.0f));
  float* vp = vall + (size_t)(b*256 + c) * 4096;
  #pragma unroll
  for (int ii = 0; ii < 16; ++ii) {
    const int pix = ii*256 + tid;
    vp[pix] = acc[ii] + vg * g3[pix];
  }
}

// ---------------------------------------------------------------------------
// h-GEMM (fp32, verified): v_mod[b,d,hw] = sum_c h_w[d,c]*v_all[b,c,hw]+h_b[d]
// written permuted: vlin[b][m = d*16+hw/256][hw%256]
// ---------------------------------------------------------------------------
__global__ __launch_bounds__(256) void gemm_h(
    const float* __restrict__ vall, const float* __restrict__ hwm,
    const float* __restrict__ hb, float* __restrict__ vlin) {
  __shared__ float As[32][65];   // [c][hw]
  __shared__ float Bs[64][33];   // [d][c]
  const int tid = threadIdx.x;
  const int hw0 = blockIdx.x * 64, d0 = blockIdx.y * 64, b = blockIdx.z;
  const int ty = tid >> 4, tx = tid & 15;
  float acc[4][4] = {};
  for (int c0 = 0; c0 < 256; c0 += 32) {
    const int cc = tid >> 3, hwi = (tid & 7) * 8;
    const float4* vp = (const float4*)(vall + (size_t)(b*256 + c0 + cc)*4096 + hw0 + hwi);
    float4 a0 = vp[0], a1 = vp[1];
    As[cc][hwi+0]=a0.x; As[cc][hwi+1]=a0.y; As[cc][hwi+2]=a0.z; As[cc][hwi+3]=a0.w;
    As[cc][hwi+4]=a1.x; As[cc][hwi+5]=a1.y; As[cc][hwi+6]=a1.z; As[cc][hwi+7]=a1.w;
    const int dd = tid & 63, cq = (tid >> 6) * 8;
    const float4* wp = (const float4*)(hwm + (size_t)(d0 + dd)*256 + c0 + cq);
    float4 b0 = wp[0], b1 = wp[1];
    Bs[dd][cq+0]=b0.x; Bs[dd][cq+1]=b0.y; Bs[dd][cq+2]=b0.z; Bs[dd][cq+3]=b0.w;
    Bs[dd][cq+4]=b1.x; Bs[dd][cq+5]=b1.y; Bs[dd][cq+6]=b1.z; Bs[dd][cq+7]=b1.w;
    __syncthreads();
    #pragma unroll
    for (int k = 0; k < 32; ++k) {
      float a[4], bv[4];
      #pragma unroll
      for (int i = 0; i < 4; ++i) a[i] = As[k][ty*4+i];
      #pragma unroll
      for (int j = 0; j < 4; ++j) bv[j] = Bs[tx*4+j][k];
      #pragma unroll
      for (int i = 0; i < 4; ++i)
        #pragma unroll
        for (int j = 0; j < 4; ++j) acc[i][j] += a[i] * bv[j];
    }
    __syncthreads();
  }
  #pragma unroll
  for (int j = 0; j < 4; ++j) {
    const int d = d0 + tx*4 + j;
    const float bb = hb[d];
    #pragma unroll
    for (int i = 0; i < 4; ++i) {
      const int hw = hw0 + ty*4 + i;
      const int m = d*16 + (hw >> 8);
      vlin[((size_t)b*4096 + m)*256 + (hw & 255)] = acc[i][j] + bb;
    }
  }
}

// ---------------------------------------------------------------------------
// Transpose+convert: vT[b][dim][m] (bf16) from vlin[b][m][dim] (fp32).
// ---------------------------------------------------------------------------
__global__ __launch_bounds__(256) void vtrans(
    const float* __restrict__ vlin, unsigned short* __restrict__ vT) {
  __shared__ float T[64][65];
  const int tid = threadIdx.x;
  const int m0 = blockIdx.x * 64, d0 = blockIdx.y * 64, b = blockIdx.z;
  const int r = tid >> 2, ck = (tid & 3) * 16;
  const float4* src = (const float4*)(vlin + ((size_t)(b*4096 + m0 + r))*256 + d0 + ck);
  float4 v0 = src[0], v1 = src[1], v2 = src[2], v3 = src[3];
  T[r][ck+ 0]=v0.x; T[r][ck+ 1]=v0.y; T[r][ck+ 2]=v0.z; T[r][ck+ 3]=v0.w;
  T[r][ck+ 4]=v1.x; T[r][ck+ 5]=v1.y; T[r][ck+ 6]=v1.z; T[r][ck+ 7]=v1.w;
  T[r][ck+ 8]=v2.x; T[r][ck+ 9]=v2.y; T[r][ck+10]=v2.z; T[r][ck+11]=v2.w;
  T[r][ck+12]=v3.x; T[r][ck+13]=v3.y; T[r][ck+14]=v3.z; T[r][ck+15]=v3.w;
  __syncthreads();
  const int dd = tid >> 2, mk = (tid & 3) * 16;
  ushort4 o[4];
  #pragma unroll
  for (int q = 0; q < 4; ++q) {
    o[q].x = f2bf(T[mk + q*4 + 0][dd]);
    o[q].y = f2bf(T[mk + q*4 + 1][dd]);
    o[q].z = f2bf(T[mk + q*4 + 2][dd]);
    o[q].w = f2bf(T[mk + q*4 + 3][dd]);
  }
  ushort4* dst = (ushort4*)&vT[((size_t)(b*256 + d0 + dd))*4096 + m0 + mk];
  dst[0] = o[0]; dst[1] = o[1]; dst[2] = o[2]; dst[3] = o[3];
}

// ---------------------------------------------------------------------------
// FUSED attention + PV with bf16 MFMA.
// Block = (bh, 16-row n-tile), 4 waves each own an m-quarter (1024).
// Pass 1: rowsums. Pass 2: normalized p -> attn store, p-tile staged in
// per-wave LDS [16n][40m-pad] bf16 (row=n on lane, k=m = pv A-frag layout),
// PV MFMA against vT B-frags every 32 m. Cross-wave LDS reduce -> aout.
// grid = 1024 (bh = blk & 63 for XCD locality of K and V slices).
// ---------------------------------------------------------------------------
__global__ __launch_bounds__(256) void attn_pv(
    const unsigned short* __restrict__ qb, const unsigned short* __restrict__ kb,
    const unsigned short* __restrict__ vt, float* __restrict__ attn,
    float* __restrict__ aout) {
  const int blk = blockIdx.x;
  const int bh = blk & 63, nt = blk >> 6;
  const int b = bh >> 3, h = bh & 7;
  const int tid = threadIdx.x;
  const int w = tid >> 6, l = tid & 63;
  const int lr = l & 15, lk = l >> 4;
  const int n0 = nt * 16;
  __shared__ float rs[4][16];
  __shared__ unsigned short pl[4][16][40];
  __shared__ float osum[4][16][32];
  bf16x8 aq = *reinterpret_cast<const bf16x8*>(
      qb + ((size_t)(b*256 + n0 + lr))*256 + h*32 + lk*8);
  const unsigned short* kbase = kb + (size_t)b*4096*256 + h*32 + lk*8;
  // pass 1: row sums
  float sum[4] = {0.f, 0.f, 0.f, 0.f};
  #pragma unroll 2
  for (int mt = 0; mt < 64; ++mt) {
    const int m0 = w*1024 + mt*16;
    bf16x8 bk = *reinterpret_cast<const bf16x8*>(kbase + (size_t)(m0 + lr)*256);
    f32x4 d = __builtin_amdgcn_mfma_f32_16x16x32_bf16(aq, bk, (f32x4){0.f,0.f,0.f,0.f}, 0, 0, 0);
    #pragma unroll
    for (int r = 0; r < 4; ++r) sum[r] += __expf(d[r] * CSCALE);
  }
  #pragma unroll
  for (int r = 0; r < 4; ++r) {
    #pragma unroll
    for (int m = 1; m < 16; m <<= 1) sum[r] += __shfl_xor(sum[r], m, 64);
  }
  if (lr == 0) {
    #pragma unroll
    for (int r = 0; r < 4; ++r) rs[w][lk*4 + r] = sum[r];
  }
  __syncthreads();
  float invS[4];
  #pragma unroll
  for (int r = 0; r < 4; ++r) {
    const int rowi = lk*4 + r;
    invS[r] = 1.0f / (rs[0][rowi] + rs[1][rowi] + rs[2][rowi] + rs[3][rowi]);
  }
  // pass 2: attn store + PV
  float* ab = attn + ((size_t)bh*256 + n0) * 4096;
  const unsigned short* vb = vt + ((size_t)(b*256 + h*32))*4096;
  f32x4 acc0 = {0.f,0.f,0.f,0.f}, acc1 = {0.f,0.f,0.f,0.f};
  for (int mt = 0; mt < 64; ++mt) {
    const int m0 = w*1024 + mt*16;
    bf16x8 bk = *reinterpret_cast<const bf16x8*>(kbase + (size_t)(m0 + lr)*256);
    f32x4 d = __builtin_amdgcn_mfma_f32_16x16x32_bf16(aq, bk, (f32x4){0.f,0.f,0.f,0.f}, 0, 0, 0);
    const int mo = (mt & 1) << 4;
    #pragma unroll
    for (int r = 0; r < 4; ++r) {
      const float p = __expf(d[r] * CSCALE) * invS[r];
      ab[(size_t)(lk*4 + r)*4096 + m0 + lr] = p;
      pl[w][lk*4 + r][mo + lr] = f2bf(p);
    }
    if (mt & 1) {
      const int mb = w*1024 + (mt - 1)*16;
      bf16x8 pa = *reinterpret_cast<const bf16x8*>(&pl[w][lr][lk*8]);
      bf16x8 bv0 = *reinterpret_cast<const bf16x8*>(vb + (size_t)lr*4096 + mb + lk*8);
      bf16x8 bv1 = *reinterpret_cast<const bf16x8*>(vb + (size_t)(16 + lr)*4096 + mb + lk*8);
      acc0 = __builtin_amdgcn_mfma_f32_16x16x32_bf16(pa, bv0, acc0, 0, 0, 0);
      acc1 = __builtin_amdgcn_mfma_f32_16x16x32_bf16(pa, bv1, acc1, 0, 0, 0);
    }
  }
  #pragma unroll
  for (int r = 0; r < 4; ++r) {
    osum[w][lk*4 + r][lr]      = acc0[r];
    osum[w][lk*4 + r][16 + lr] = acc1[r];
  }
  __syncthreads();
  for (int i = tid; i < 512; i += 256) {
    const int n = i >> 5, d = i & 31;
    const float s = osum[0][n][d] + osum[1][n][d] + osum[2][n][d] + osum[3][n][d];
    aout[((size_t)(b*256 + n0 + n))*256 + h*32 + d] = s;
  }
}

} // namespace

extern "C" void kernel_launch(void* const* d_in, const int* in_sizes, int n_in,
                              void* d_out, int out_size, void* d_ws, size_t ws_size,
                              hipStream_t stream) {
  (void)in_sizes; (void)n_in; (void)out_size; (void)ws_size;
  const float* latents = (const float*)d_in[0];
  const float* context = (const float*)d_in[1];
  const float* q_w    = (const float*)d_in[2];
  const float* k_w    = (const float*)d_in[3];
  const float* f_w    = (const float*)d_in[4];
  const float* f_b    = (const float*)d_in[5];
  const float* h_w    = (const float*)d_in[6];
  const float* h_b    = (const float*)d_in[7];
  const float* fk0    = (const float*)d_in[8];
  const float* fk1    = (const float*)d_in[9];
  const float* fk2    = (const float*)d_in[10];
  const float* proj_w = (const float*)d_in[11];
  const float* proj_b = (const float*)d_in[12];

  float* out0 = (float*)d_out;                  // (8,256,256)
  float* attn = out0 + (size_t)8*256*256;       // (8,8,256,4096)

  // workspace layout (byte offsets)
  char* w = (char*)d_ws;
  unsigned short* q_bf = (unsigned short*)(w + 0x0);        //  1 MB  (8,256,256) bf16
  unsigned short* k_bf = (unsigned short*)(w + 0x100000);   // 16 MB  (8,4096,256) bf16
  unsigned short* v_tb = (unsigned short*)(w + 0x1100000);  // 16 MB  (8,256,4096) bf16 vT[dim][m]
  float* buf1  = (float*)(w + 0x2100000);                   // 32 MB  (vctx planar)
  float* buf2  = (float*)(w + 0x4100000);                   // 32 MB  (vlin)
  float* gates = (float*)(w + 0x6100000);                   // 0.5 MB
  float* vall  = (float*)(w + 0x6180000);                   // 32 MB
  float* aout  = (float*)(w + 0x8180000);                   //  2 MB
  float* vlin  = buf2;

  gemm_xwt_bf16<<<dim3(32, 4),  256, 0, stream>>>(latents, q_w, q_bf);
  gemm_xwt_bf16<<<dim3(512, 4), 256, 0, stream>>>(context, k_w, k_bf);
  gemm_f    <<<dim3(512, 5), 256, 0, stream>>>(context, f_w, f_b, buf1, gates);
  fused_conv<<<2048, 256, 0, stream>>>(buf1, fk0, fk1, fk2, gates, vall);
  gemm_h    <<<dim3(64, 4, 8), 256, 0, stream>>>(vall, h_w, h_b, vlin);
  vtrans    <<<dim3(64, 4, 8), 256, 0, stream>>>(vlin, v_tb);
  attn_pv   <<<1024, 256, 0, stream>>>(q_bf, k_bf, v_tb, attn, aout);
  gemm_xwt  <<<dim3(32, 4), 256, 0, stream>>>(aout, proj_w, proj_b, out0, 256);
}

// Round 7
// 386.421 us; speedup vs baseline: 3.0423x; 1.4466x over previous
//
#include <hip/hip_runtime.h>
#include <math.h>

// Shapes: B=8, N_L=256, C=256, NH=8, HD=32, H=W=64, N_C=4096, L=3, KS={3,5,7}
// Reference reshape semantics: v[b][m][dim] with m = c*16 + (hw>>8), dim = hw&255.

namespace {

constexpr float CSCALE = 0.17677669529663688f;

typedef __attribute__((ext_vector_type(8))) __bf16 bf16x8;
typedef __attribute__((ext_vector_type(4))) float f32x4;

__device__ __forceinline__ float gelu_f(float x) {
  return 0.5f * x * (1.0f + erff(x * 0.70710678118654752f));
}

__device__ __forceinline__ unsigned short f2bf(float f) {
  union { float f; unsigned u; } v; v.f = f;
  unsigned r = v.u + 0x7fffu + ((v.u >> 16) & 1u);  // RNE
  return (unsigned short)(r >> 16);
}

__device__ __forceinline__ float bf2f(unsigned short u) {
  union { unsigned u; float f; } v; v.u = (unsigned)u << 16;
  return v.f;
}

// ---------------------------------------------------------------------------
// Cast fp32 -> bf16 for context, latents, and the 5 weight matrices.
// Block ranges (1024 float4-quads per block):
//   [0,2048) ctx | [2048,2176) lat | +16 qw | +16 kw | +17 fw | +16 hw | +16 pw
// ---------------------------------------------------------------------------
__global__ __launch_bounds__(256) void cast_all(
    const float* __restrict__ ctx, const float* __restrict__ lat,
    const float* __restrict__ qw, const float* __restrict__ kw,
    const float* __restrict__ fw, const float* __restrict__ hww,
    const float* __restrict__ pw,
    unsigned short* ctxb, unsigned short* latb, unsigned short* qwb,
    unsigned short* kwb, unsigned short* fwb, unsigned short* hwb,
    unsigned short* pwb) {
  const int blk = blockIdx.x;
  const float* s; unsigned short* d; int b0, nq;
  if      (blk < 2048) { s = ctx; d = ctxb; b0 = blk;        nq = 2097152; }
  else if (blk < 2176) { s = lat; d = latb; b0 = blk - 2048; nq = 131072; }
  else if (blk < 2192) { s = qw;  d = qwb;  b0 = blk - 2176; nq = 16384; }
  else if (blk < 2208) { s = kw;  d = kwb;  b0 = blk - 2192; nq = 16384; }
  else if (blk < 2225) { s = fw;  d = fwb;  b0 = blk - 2208; nq = 16640; }
  else if (blk < 2241) { s = hww; d = hwb;  b0 = blk - 2225; nq = 16384; }
  else                 { s = pw;  d = pwb;  b0 = blk - 2241; nq = 16384; }
  #pragma unroll
  for (int t = 0; t < 4; ++t) {
    const int q = b0*1024 + t*256 + threadIdx.x;
    if (q < nq) {
      float4 v = ((const float4*)s)[q];
      ushort4 o;
      o.x = f2bf(v.x); o.y = f2bf(v.y); o.z = f2bf(v.z); o.w = f2bf(v.w);
      ((ushort4*)d)[q] = o;
    }
  }
}

// ---------------------------------------------------------------------------
// MFMA GEMM, bf16 in -> bf16 out (no bias): out[r][n] = A[r][:] . W[n][:]
// K=256, N=256. Direct fragments (both operands k-contiguous), no LDS.
// Block: 64 rows x 64 cols; wave w owns rows [r0+w*16, +16). grid (M/64, 4).
// Frag/layout convention verified by attn_mfma (rounds 5/6).
// ---------------------------------------------------------------------------
__global__ __launch_bounds__(256) void mfma_qk(
    const unsigned short* __restrict__ A, const unsigned short* __restrict__ W,
    unsigned short* __restrict__ out) {
  const int r0 = blockIdx.x * 64, n0 = blockIdx.y * 64;
  const int tid = threadIdx.x, w = tid >> 6, l = tid & 63;
  const int lr = l & 15, lk = l >> 4;
  const int rw = r0 + w*16;
  const unsigned short* ap = A + (size_t)(rw + lr)*256 + lk*8;
  f32x4 acc[4] = {{0.f,0.f,0.f,0.f},{0.f,0.f,0.f,0.f},{0.f,0.f,0.f,0.f},{0.f,0.f,0.f,0.f}};
  #pragma unroll
  for (int k0 = 0; k0 < 256; k0 += 32) {
    bf16x8 a = *reinterpret_cast<const bf16x8*>(ap + k0);
    #pragma unroll
    for (int j = 0; j < 4; ++j) {
      bf16x8 b = *reinterpret_cast<const bf16x8*>(W + (size_t)(n0 + j*16 + lr)*256 + k0 + lk*8);
      acc[j] = __builtin_amdgcn_mfma_f32_16x16x32_bf16(a, b, acc[j], 0, 0, 0);
    }
  }
  #pragma unroll
  for (int j = 0; j < 4; ++j)
    #pragma unroll
    for (int rr = 0; rr < 4; ++rr)
      out[(size_t)(rw + lk*4 + rr)*256 + n0 + j*16 + lr] = f2bf(acc[j][rr]);
}

// ---------------------------------------------------------------------------
// MFMA f-projection: rows r = b*4096+hw over bf16 ctx, W rows n in [0,260).
// n<256 -> vctx[b][n][hw] (bf16 planar, ushort4), else gates (fp32, float4).
// grid (512, 5); tail tile (n0=256) guarded.
// ---------------------------------------------------------------------------
__global__ __launch_bounds__(256) void mfma_f(
    const unsigned short* __restrict__ A, const unsigned short* __restrict__ W,
    const float* __restrict__ fb, unsigned short* __restrict__ vctx,
    float* __restrict__ gates) {
  const int r0 = blockIdx.x * 64, n0 = blockIdx.y * 64;
  const int tid = threadIdx.x, w = tid >> 6, l = tid & 63;
  const int lr = l & 15, lk = l >> 4;
  const int rw = r0 + w*16;
  const unsigned short* ap = A + (size_t)(rw + lr)*256 + lk*8;
  f32x4 acc[4] = {{0.f,0.f,0.f,0.f},{0.f,0.f,0.f,0.f},{0.f,0.f,0.f,0.f},{0.f,0.f,0.f,0.f}};
  #pragma unroll
  for (int k0 = 0; k0 < 256; k0 += 32) {
    bf16x8 a = *reinterpret_cast<const bf16x8*>(ap + k0);
    #pragma unroll
    for (int j = 0; j < 4; ++j) {
      const int n = n0 + j*16 + lr;
      bf16x8 b = {};
      if (n < 260)
        b = *reinterpret_cast<const bf16x8*>(W + (size_t)n*256 + k0 + lk*8);
      acc[j] = __builtin_amdgcn_mfma_f32_16x16x32_bf16(a, b, acc[j], 0, 0, 0);
    }
  }
  const int rbase = rw + lk*4;
  const int b = rbase >> 12, hw = rbase & 4095;
  #pragma unroll
  for (int j = 0; j < 4; ++j) {
    const int n = n0 + j*16 + lr;
    if (n >= 260) continue;
    const float bb = fb[n];
    if (n < 256) {
      ushort4 o;
      o.x = f2bf(acc[j][0] + bb); o.y = f2bf(acc[j][1] + bb);
      o.z = f2bf(acc[j][2] + bb); o.w = f2bf(acc[j][3] + bb);
      *(ushort4*)&vctx[((size_t)(b*256 + n))*4096 + hw] = o;
    } else {
      float4 o = make_float4(acc[j][0] + bb, acc[j][1] + bb,
                             acc[j][2] + bb, acc[j][3] + bb);
      *(float4*)&gates[((size_t)(b*4 + (n - 256)))*4096 + hw] = o;
    }
  }
}

// ---------------------------------------------------------------------------
// FUSED depthwise conv chain (bf16 in/out, IN-PLACE: in == out is safe since
// each block stages its entire plane into LDS before writing).
// conv3+gelu -> conv5+gelu -> conv7+gelu (+global-mean term), gated accum.
// One (b,c) 64x64 plane per block, grid = 2048.
// ---------------------------------------------------------------------------
__global__ __launch_bounds__(256) void fused_conv(
    const unsigned short* in, const float* __restrict__ wk3,
    const float* __restrict__ wk5, const float* __restrict__ wk7,
    const float* __restrict__ gates, unsigned short* out) {
  constexpr int TW = 70;  // 64 + 2*3 frame
  __shared__ float A[TW * TW];
  __shared__ float w3[9];
  __shared__ float w5[25];
  __shared__ float w7[49];
  __shared__ float red[4];
  const int tid = threadIdx.x;
  const int b = blockIdx.x >> 8, c = blockIdx.x & 255;
  if (tid < 9)  w3[tid] = wk3[c*9  + tid];
  else if (tid < 34) w5[tid-9]  = wk5[c*25 + tid-9];
  else if (tid < 83) w7[tid-34] = wk7[c*49 + tid-34];
  const unsigned short* ip = in + (size_t)(b*256 + c) * 4096;
  for (int idx = tid; idx < TW*TW; idx += 256) {
    const int ty = idx / TW, tx = idx - ty*TW;
    const int gy = ty - 3, gx = tx - 3;
    A[idx] = (gy >= 0 && gy < 64 && gx >= 0 && gx < 64) ? bf2f(ip[gy*64 + gx]) : 0.0f;
  }
  __syncthreads();
  const float* g0 = gates + (size_t)(b*4 + 0) * 4096;
  const float* g1 = gates + (size_t)(b*4 + 1) * 4096;
  const float* g2 = gates + (size_t)(b*4 + 2) * 4096;
  const float* g3 = gates + (size_t)(b*4 + 3) * 4096;
  float v[16], acc[16];
  // ---- conv3 + gelu ----
  #pragma unroll
  for (int ii = 0; ii < 16; ++ii) {
    const int pix = ii*256 + tid;
    const int y = pix >> 6, x = pix & 63;
    float s = 0.f;
    #pragma unroll
    for (int ky = 0; ky < 3; ++ky)
      #pragma unroll
      for (int kx = 0; kx < 3; ++kx)
        s += w3[ky*3 + kx] * A[(y+2+ky)*TW + (x+2+kx)];
    v[ii] = gelu_f(s);
    acc[ii] = v[ii] * g0[pix];
  }
  __syncthreads();
  #pragma unroll
  for (int ii = 0; ii < 16; ++ii) {
    const int pix = ii*256 + tid;
    A[((pix >> 6) + 3)*TW + (pix & 63) + 3] = v[ii];
  }
  __syncthreads();
  // ---- conv5 + gelu ----
  #pragma unroll
  for (int ii = 0; ii < 16; ++ii) {
    const int pix = ii*256 + tid;
    const int y = pix >> 6, x = pix & 63;
    float s = 0.f;
    #pragma unroll
    for (int ky = 0; ky < 5; ++ky)
      #pragma unroll
      for (int kx = 0; kx < 5; ++kx)
        s += w5[ky*5 + kx] * A[(y+1+ky)*TW + (x+1+kx)];
    v[ii] = gelu_f(s);
    acc[ii] += v[ii] * g1[pix];
  }
  __syncthreads();
  #pragma unroll
  for (int ii = 0; ii < 16; ++ii) {
    const int pix = ii*256 + tid;
    A[((pix >> 6) + 3)*TW + (pix & 63) + 3] = v[ii];
  }
  __syncthreads();
  // ---- conv7 + gelu (+ mean) ----
  float msum = 0.f;
  #pragma unroll
  for (int ii = 0; ii < 16; ++ii) {
    const int pix = ii*256 + tid;
    const int y = pix >> 6, x = pix & 63;
    float s = 0.f;
    #pragma unroll
    for (int ky = 0; ky < 7; ++ky)
      #pragma unroll
      for (int kx = 0; kx < 7; ++kx)
        s += w7[ky*7 + kx] * A[(y+ky)*TW + (x+kx)];
    v[ii] = gelu_f(s);
    acc[ii] += v[ii] * g2[pix];
    msum += v[ii];
  }
  #pragma unroll
  for (int off = 32; off >= 1; off >>= 1) msum += __shfl_xor(msum, off, 64);
  if ((tid & 63) == 0) red[tid >> 6] = msum;
  __syncthreads();
  const float vg = gelu_f((red[0]+red[1]+red[2]+red[3]) * (1.0f/4096.0f));
  unsigned short* vp = out + (size_t)(b*256 + c) * 4096;
  #pragma unroll
  for (int ii = 0; ii < 16; ++ii) {
    const int pix = ii*256 + tid;
    vp[pix] = f2bf(acc[ii] + vg * g3[pix]);
  }
}

// ---------------------------------------------------------------------------
// MFMA h-GEMM: v_mod[b,d,hw] = sum_c h_w[d,c]*vall[b,c,hw] + h_b[d], writing
// v_tb[b][dim][m] DIRECTLY (dim=hw&255, m=d*16+hw>>8) via 2B scatter stores.
// Block: 64 d x 64 hw, full K=256 staged in LDS transposed [hw][c] (pad 264
// keeps b128 reads 16B-aligned; lane stride 528B -> 2-way bank alias = free).
// grid (64 hw-tiles, 4 d-tiles, 8 b).
// ---------------------------------------------------------------------------
__global__ __launch_bounds__(256) void mfma_h(
    const unsigned short* __restrict__ vall, const unsigned short* __restrict__ hwb,
    const float* __restrict__ hb, unsigned short* __restrict__ vt) {
  __shared__ unsigned short Bs[64][264];
  const int hw0 = blockIdx.x * 64, d0 = blockIdx.y * 64, b = blockIdx.z;
  const int tid = threadIdx.x, w = tid >> 6, l = tid & 63;
  const int lr = l & 15, lk = l >> 4;
  const int cl = tid >> 3, hl = (tid & 7) * 8;
  #pragma unroll
  for (int c0 = 0; c0 < 256; c0 += 32) {
    const unsigned short* sp = vall + (size_t)(b*256 + c0 + cl)*4096 + hw0 + hl;
    ushort4 u0 = *(const ushort4*)sp;
    ushort4 u1 = *(const ushort4*)(sp + 4);
    Bs[hl+0][c0+cl] = u0.x; Bs[hl+1][c0+cl] = u0.y;
    Bs[hl+2][c0+cl] = u0.z; Bs[hl+3][c0+cl] = u0.w;
    Bs[hl+4][c0+cl] = u1.x; Bs[hl+5][c0+cl] = u1.y;
    Bs[hl+6][c0+cl] = u1.z; Bs[hl+7][c0+cl] = u1.w;
  }
  __syncthreads();
  const int dw = d0 + w*16;
  const unsigned short* ap = hwb + (size_t)(dw + lr)*256 + lk*8;
  f32x4 acc[4] = {{0.f,0.f,0.f,0.f},{0.f,0.f,0.f,0.f},{0.f,0.f,0.f,0.f},{0.f,0.f,0.f,0.f}};
  #pragma unroll
  for (int k0 = 0; k0 < 256; k0 += 32) {
    bf16x8 a = *reinterpret_cast<const bf16x8*>(ap + k0);
    #pragma unroll
    for (int j = 0; j < 4; ++j) {
      bf16x8 bv = *reinterpret_cast<const bf16x8*>(&Bs[j*16 + lr][k0 + lk*8]);
      acc[j] = __builtin_amdgcn_mfma_f32_16x16x32_bf16(a, bv, acc[j], 0, 0, 0);
    }
  }
  const int q = hw0 >> 8, dim0 = hw0 & 255;
  float hbv[4];
  #pragma unroll
  for (int rr = 0; rr < 4; ++rr) hbv[rr] = hb[dw + lk*4 + rr];
  #pragma unroll
  for (int j = 0; j < 4; ++j) {
    const int dim = dim0 + j*16 + lr;
    unsigned short* vrow = vt + ((size_t)(b*256 + dim))*4096 + q;
    #pragma unroll
    for (int rr = 0; rr < 4; ++rr) {
      const int d = dw + lk*4 + rr;
      vrow[d*16] = f2bf(acc[j][rr] + hbv[rr]);
    }
  }
}

// ---------------------------------------------------------------------------
// FUSED attention + PV with bf16 MFMA (verified round 6); aout now bf16.
// Block = (bh, 16-row n-tile), 4 waves each own an m-quarter (1024).
// grid = 1024 (bh = blk & 63 for XCD locality of K and V slices).
// ---------------------------------------------------------------------------
__global__ __launch_bounds__(256) void attn_pv(
    const unsigned short* __restrict__ qb, const unsigned short* __restrict__ kb,
    const unsigned short* __restrict__ vt, float* __restrict__ attn,
    unsigned short* __restrict__ aout) {
  const int blk = blockIdx.x;
  const int bh = blk & 63, nt = blk >> 6;
  const int b = bh >> 3, h = bh & 7;
  const int tid = threadIdx.x;
  const int w = tid >> 6, l = tid & 63;
  const int lr = l & 15, lk = l >> 4;
  const int n0 = nt * 16;
  __shared__ float rs[4][16];
  __shared__ unsigned short pl[4][16][40];
  __shared__ float osum[4][16][32];
  bf16x8 aq = *reinterpret_cast<const bf16x8*>(
      qb + ((size_t)(b*256 + n0 + lr))*256 + h*32 + lk*8);
  const unsigned short* kbase = kb + (size_t)b*4096*256 + h*32 + lk*8;
  // pass 1: row sums
  float sum[4] = {0.f, 0.f, 0.f, 0.f};
  #pragma unroll 2
  for (int mt = 0; mt < 64; ++mt) {
    const int m0 = w*1024 + mt*16;
    bf16x8 bk = *reinterpret_cast<const bf16x8*>(kbase + (size_t)(m0 + lr)*256);
    f32x4 d = __builtin_amdgcn_mfma_f32_16x16x32_bf16(aq, bk, (f32x4){0.f,0.f,0.f,0.f}, 0, 0, 0);
    #pragma unroll
    for (int r = 0; r < 4; ++r) sum[r] += __expf(d[r] * CSCALE);
  }
  #pragma unroll
  for (int r = 0; r < 4; ++r) {
    #pragma unroll
    for (int m = 1; m < 16; m <<= 1) sum[r] += __shfl_xor(sum[r], m, 64);
  }
  if (lr == 0) {
    #pragma unroll
    for (int r = 0; r < 4; ++r) rs[w][lk*4 + r] = sum[r];
  }
  __syncthreads();
  float invS[4];
  #pragma unroll
  for (int r = 0; r < 4; ++r) {
    const int rowi = lk*4 + r;
    invS[r] = 1.0f / (rs[0][rowi] + rs[1][rowi] + rs[2][rowi] + rs[3][rowi]);
  }
  // pass 2: attn store + PV
  float* ab = attn + ((size_t)bh*256 + n0) * 4096;
  const unsigned short* vb = vt + ((size_t)(b*256 + h*32))*4096;
  f32x4 acc0 = {0.f,0.f,0.f,0.f}, acc1 = {0.f,0.f,0.f,0.f};
  for (int mt = 0; mt < 64; ++mt) {
    const int m0 = w*1024 + mt*16;
    bf16x8 bk = *reinterpret_cast<const bf16x8*>(kbase + (size_t)(m0 + lr)*256);
    f32x4 d = __builtin_amdgcn_mfma_f32_16x16x32_bf16(aq, bk, (f32x4){0.f,0.f,0.f,0.f}, 0, 0, 0);
    const int mo = (mt & 1) << 4;
    #pragma unroll
    for (int r = 0; r < 4; ++r) {
      const float p = __expf(d[r] * CSCALE) * invS[r];
      ab[(size_t)(lk*4 + r)*4096 + m0 + lr] = p;
      pl[w][lk*4 + r][mo + lr] = f2bf(p);
    }
    if (mt & 1) {
      const int mb = w*1024 + (mt - 1)*16;
      bf16x8 pa = *reinterpret_cast<const bf16x8*>(&pl[w][lr][lk*8]);
      bf16x8 bv0 = *reinterpret_cast<const bf16x8*>(vb + (size_t)lr*4096 + mb + lk*8);
      bf16x8 bv1 = *reinterpret_cast<const bf16x8*>(vb + (size_t)(16 + lr)*4096 + mb + lk*8);
      acc0 = __builtin_amdgcn_mfma_f32_16x16x32_bf16(pa, bv0, acc0, 0, 0, 0);
      acc1 = __builtin_amdgcn_mfma_f32_16x16x32_bf16(pa, bv1, acc1, 0, 0, 0);
    }
  }
  #pragma unroll
  for (int r = 0; r < 4; ++r) {
    osum[w][lk*4 + r][lr]      = acc0[r];
    osum[w][lk*4 + r][16 + lr] = acc1[r];
  }
  __syncthreads();
  for (int i = tid; i < 512; i += 256) {
    const int n = i >> 5, d = i & 31;
    const float s = osum[0][n][d] + osum[1][n][d] + osum[2][n][d] + osum[3][n][d];
    aout[((size_t)(b*256 + n0 + n))*256 + h*32 + d] = f2bf(s);
  }
}

// ---------------------------------------------------------------------------
// MFMA proj: out0[r][n] = aout[r][:] . proj_w[n][:] + proj_b[n]  (fp32 out)
// grid (32, 4).
// ---------------------------------------------------------------------------
__global__ __launch_bounds__(256) void mfma_proj(
    const unsigned short* __restrict__ A, const unsigned short* __restrict__ W,
    const float* __restrict__ pb, float* __restrict__ out) {
  const int r0 = blockIdx.x * 64, n0 = blockIdx.y * 64;
  const int tid = threadIdx.x, w = tid >> 6, l = tid & 63;
  const int lr = l & 15, lk = l >> 4;
  const int rw = r0 + w*16;
  const unsigned short* ap = A + (size_t)(rw + lr)*256 + lk*8;
  f32x4 acc[4] = {{0.f,0.f,0.f,0.f},{0.f,0.f,0.f,0.f},{0.f,0.f,0.f,0.f},{0.f,0.f,0.f,0.f}};
  #pragma unroll
  for (int k0 = 0; k0 < 256; k0 += 32) {
    bf16x8 a = *reinterpret_cast<const bf16x8*>(ap + k0);
    #pragma unroll
    for (int j = 0; j < 4; ++j) {
      bf16x8 b = *reinterpret_cast<const bf16x8*>(W + (size_t)(n0 + j*16 + lr)*256 + k0 + lk*8);
      acc[j] = __builtin_amdgcn_mfma_f32_16x16x32_bf16(a, b, acc[j], 0, 0, 0);
    }
  }
  #pragma unroll
  for (int j = 0; j < 4; ++j) {
    const int n = n0 + j*16 + lr;
    const float bb = pb[n];
    #pragma unroll
    for (int rr = 0; rr < 4; ++rr)
      out[(size_t)(rw + lk*4 + rr)*256 + n] = acc[j][rr] + bb;
  }
}

} // namespace

extern "C" void kernel_launch(void* const* d_in, const int* in_sizes, int n_in,
                              void* d_out, int out_size, void* d_ws, size_t ws_size,
                              hipStream_t stream) {
  (void)in_sizes; (void)n_in; (void)out_size; (void)ws_size;
  const float* latents = (const float*)d_in[0];
  const float* context = (const float*)d_in[1];
  const float* q_w    = (const float*)d_in[2];
  const float* k_w    = (const float*)d_in[3];
  const float* f_w    = (const float*)d_in[4];
  const float* f_b    = (const float*)d_in[5];
  const float* h_w    = (const float*)d_in[6];
  const float* h_b    = (const float*)d_in[7];
  const float* fk0    = (const float*)d_in[8];
  const float* fk1    = (const float*)d_in[9];
  const float* fk2    = (const float*)d_in[10];
  const float* proj_w = (const float*)d_in[11];
  const float* proj_b = (const float*)d_in[12];

  float* out0 = (float*)d_out;                  // (8,256,256)
  float* attn = out0 + (size_t)8*256*256;       // (8,8,256,4096)

  // workspace layout (byte offsets), total ~74 MB
  char* w = (char*)d_ws;
  unsigned short* ctx_bf = (unsigned short*)(w + 0x0);        // 16 MB (8,4096,256)
  unsigned short* vcv    = (unsigned short*)(w + 0x1000000);  // 16 MB vctx/vall (in-place conv)
  unsigned short* k_bf   = (unsigned short*)(w + 0x2100000);  // 16 MB (8,4096,256)
  unsigned short* v_tb   = (unsigned short*)(w + 0x3100000);  // 16 MB (8,256,4096) vT[dim][m]
  unsigned short* q_bf   = (unsigned short*)(w + 0x4100000);  //  1 MB (8,256,256)
  unsigned short* lat_bf = (unsigned short*)(w + 0x4200000);  //  1 MB
  unsigned short* qw_bf  = (unsigned short*)(w + 0x4300000);  // 128 KB
  unsigned short* kw_bf  = (unsigned short*)(w + 0x4340000);  // 128 KB
  unsigned short* fw_bf  = (unsigned short*)(w + 0x4380000);  // 130 KB
  unsigned short* hw_bf  = (unsigned short*)(w + 0x43C0000);  // 128 KB
  unsigned short* pw_bf  = (unsigned short*)(w + 0x4400000);  // 128 KB
  float*          gates  = (float*)(w + 0x4440000);           // 512 KB fp32
  unsigned short* aout_bf= (unsigned short*)(w + 0x44C0000);  //  1 MB

  cast_all<<<2257, 256, 0, stream>>>(context, latents, q_w, k_w, f_w, h_w, proj_w,
                                     ctx_bf, lat_bf, qw_bf, kw_bf, fw_bf, hw_bf, pw_bf);
  mfma_qk  <<<dim3(32, 4),  256, 0, stream>>>(lat_bf, qw_bf, q_bf);
  mfma_qk  <<<dim3(512, 4), 256, 0, stream>>>(ctx_bf, kw_bf, k_bf);
  mfma_f   <<<dim3(512, 5), 256, 0, stream>>>(ctx_bf, fw_bf, f_b, vcv, gates);
  fused_conv<<<2048, 256, 0, stream>>>(vcv, fk0, fk1, fk2, gates, vcv);
  mfma_h   <<<dim3(64, 4, 8), 256, 0, stream>>>(vcv, hw_bf, h_b, v_tb);
  attn_pv  <<<1024, 256, 0, stream>>>(q_bf, k_bf, v_tb, attn, aout_bf);
  mfma_proj<<<dim3(32, 4), 256, 0, stream>>>(aout_bf, pw_bf, proj_b, out0);
}

// Round 8
// 342.446 us; speedup vs baseline: 3.4330x; 1.1284x over previous
//
#include <hip/hip_runtime.h>
#include <math.h>

// Shapes: B=8, N_L=256, C=256, NH=8, HD=32, H=W=64, N_C=4096, L=3, KS={3,5,7}
// Reference reshape semantics: v[b][m][dim] with m = c*16 + (hw>>8), dim = hw&255.

namespace {

constexpr float CSCALE = 0.17677669529663688f;

typedef __attribute__((ext_vector_type(8))) __bf16 bf16x8;
typedef __attribute__((ext_vector_type(4))) float f32x4;

__device__ __forceinline__ float gelu_f(float x) {
  return 0.5f * x * (1.0f + erff(x * 0.70710678118654752f));
}

__device__ __forceinline__ unsigned short f2bf(float f) {
  union { float f; unsigned u; } v; v.f = f;
  unsigned r = v.u + 0x7fffu + ((v.u >> 16) & 1u);  // RNE
  return (unsigned short)(r >> 16);
}

__device__ __forceinline__ float bf2f(unsigned short u) {
  union { unsigned u; float f; } v; v.u = (unsigned)u << 16;
  return v.f;
}

// ---------------------------------------------------------------------------
// Cast fp32 -> bf16 for context, latents, and the 5 weight matrices.
// ---------------------------------------------------------------------------
__global__ __launch_bounds__(256) void cast_all(
    const float* __restrict__ ctx, const float* __restrict__ lat,
    const float* __restrict__ qw, const float* __restrict__ kw,
    const float* __restrict__ fw, const float* __restrict__ hww,
    const float* __restrict__ pw,
    unsigned short* ctxb, unsigned short* latb, unsigned short* qwb,
    unsigned short* kwb, unsigned short* fwb, unsigned short* hwb,
    unsigned short* pwb) {
  const int blk = blockIdx.x;
  const float* s; unsigned short* d; int b0, nq;
  if      (blk < 2048) { s = ctx; d = ctxb; b0 = blk;        nq = 2097152; }
  else if (blk < 2176) { s = lat; d = latb; b0 = blk - 2048; nq = 131072; }
  else if (blk < 2192) { s = qw;  d = qwb;  b0 = blk - 2176; nq = 16384; }
  else if (blk < 2208) { s = kw;  d = kwb;  b0 = blk - 2192; nq = 16384; }
  else if (blk < 2225) { s = fw;  d = fwb;  b0 = blk - 2208; nq = 16640; }
  else if (blk < 2241) { s = hww; d = hwb;  b0 = blk - 2225; nq = 16384; }
  else                 { s = pw;  d = pwb;  b0 = blk - 2241; nq = 16384; }
  #pragma unroll
  for (int t = 0; t < 4; ++t) {
    const int q = b0*1024 + t*256 + threadIdx.x;
    if (q < nq) {
      float4 v = ((const float4*)s)[q];
      ushort4 o;
      o.x = f2bf(v.x); o.y = f2bf(v.y); o.z = f2bf(v.z); o.w = f2bf(v.w);
      ((ushort4*)d)[q] = o;
    }
  }
}

// ---------------------------------------------------------------------------
// MFMA GEMM, bf16 in -> bf16 out (no bias). For the q projection. grid (32,4).
// ---------------------------------------------------------------------------
__global__ __launch_bounds__(256) void mfma_qk(
    const unsigned short* __restrict__ A, const unsigned short* __restrict__ W,
    unsigned short* __restrict__ out) {
  const int r0 = blockIdx.x * 64, n0 = blockIdx.y * 64;
  const int tid = threadIdx.x, w = tid >> 6, l = tid & 63;
  const int lr = l & 15, lk = l >> 4;
  const int rw = r0 + w*16;
  const unsigned short* ap = A + (size_t)(rw + lr)*256 + lk*8;
  f32x4 acc[4] = {{0.f,0.f,0.f,0.f},{0.f,0.f,0.f,0.f},{0.f,0.f,0.f,0.f},{0.f,0.f,0.f,0.f}};
  #pragma unroll
  for (int k0 = 0; k0 < 256; k0 += 32) {
    bf16x8 a = *reinterpret_cast<const bf16x8*>(ap + k0);
    #pragma unroll
    for (int j = 0; j < 4; ++j) {
      bf16x8 b = *reinterpret_cast<const bf16x8*>(W + (size_t)(n0 + j*16 + lr)*256 + k0 + lk*8);
      acc[j] = __builtin_amdgcn_mfma_f32_16x16x32_bf16(a, b, acc[j], 0, 0, 0);
    }
  }
  #pragma unroll
  for (int j = 0; j < 4; ++j)
    #pragma unroll
    for (int rr = 0; rr < 4; ++rr)
      out[(size_t)(rw + lk*4 + rr)*256 + n0 + j*16 + lr] = f2bf(acc[j][rr]);
}

// ---------------------------------------------------------------------------
// MERGED k-projection + f-projection over bf16 ctx (read ctx once per tile).
// grid (512, 9): y<4 -> k output (bf16, row-major); y>=4 -> f output with
// n in [0,260): n<256 -> vctx[b][n][hw] bf16 planar, else gates fp32.
// ---------------------------------------------------------------------------
__global__ __launch_bounds__(256) void mfma_fk(
    const unsigned short* __restrict__ A, const unsigned short* __restrict__ Wk,
    const unsigned short* __restrict__ Wf, const float* __restrict__ fb,
    unsigned short* __restrict__ kout, unsigned short* __restrict__ vctx,
    float* __restrict__ gates) {
  const int r0 = blockIdx.x * 64;
  const bool isk = blockIdx.y < 4;
  const int n0 = (isk ? blockIdx.y : blockIdx.y - 4) * 64;
  const unsigned short* W = isk ? Wk : Wf;
  const int tid = threadIdx.x, w = tid >> 6, l = tid & 63;
  const int lr = l & 15, lk = l >> 4;
  const int rw = r0 + w*16;
  const unsigned short* ap = A + (size_t)(rw + lr)*256 + lk*8;
  f32x4 acc[4] = {{0.f,0.f,0.f,0.f},{0.f,0.f,0.f,0.f},{0.f,0.f,0.f,0.f},{0.f,0.f,0.f,0.f}};
  #pragma unroll
  for (int k0 = 0; k0 < 256; k0 += 32) {
    bf16x8 a = *reinterpret_cast<const bf16x8*>(ap + k0);
    #pragma unroll
    for (int j = 0; j < 4; ++j) {
      const int n = n0 + j*16 + lr;
      bf16x8 b = {};
      if (isk || n < 260)
        b = *reinterpret_cast<const bf16x8*>(W + (size_t)n*256 + k0 + lk*8);
      acc[j] = __builtin_amdgcn_mfma_f32_16x16x32_bf16(a, b, acc[j], 0, 0, 0);
    }
  }
  if (isk) {
    #pragma unroll
    for (int j = 0; j < 4; ++j)
      #pragma unroll
      for (int rr = 0; rr < 4; ++rr)
        kout[(size_t)(rw + lk*4 + rr)*256 + n0 + j*16 + lr] = f2bf(acc[j][rr]);
  } else {
    const int rbase = rw + lk*4;
    const int b = rbase >> 12, hw = rbase & 4095;
    #pragma unroll
    for (int j = 0; j < 4; ++j) {
      const int n = n0 + j*16 + lr;
      if (n >= 260) continue;
      const float bb = fb[n];
      if (n < 256) {
        ushort4 o;
        o.x = f2bf(acc[j][0] + bb); o.y = f2bf(acc[j][1] + bb);
        o.z = f2bf(acc[j][2] + bb); o.w = f2bf(acc[j][3] + bb);
        *(ushort4*)&vctx[((size_t)(b*256 + n))*4096 + hw] = o;
      } else {
        float4 o = make_float4(acc[j][0] + bb, acc[j][1] + bb,
                               acc[j][2] + bb, acc[j][3] + bb);
        *(float4*)&gates[((size_t)(b*4 + (n - 256)))*4096 + hw] = o;
      }
    }
  }
}

// ---------------------------------------------------------------------------
// FUSED depthwise conv chain (bf16 in/out, in-place). grid = 2048.
// ---------------------------------------------------------------------------
__global__ __launch_bounds__(256) void fused_conv(
    const unsigned short* in, const float* __restrict__ wk3,
    const float* __restrict__ wk5, const float* __restrict__ wk7,
    const float* __restrict__ gates, unsigned short* out) {
  constexpr int TW = 70;
  __shared__ float A[TW * TW];
  __shared__ float w3[9];
  __shared__ float w5[25];
  __shared__ float w7[49];
  __shared__ float red[4];
  const int tid = threadIdx.x;
  const int b = blockIdx.x >> 8, c = blockIdx.x & 255;
  if (tid < 9)  w3[tid] = wk3[c*9  + tid];
  else if (tid < 34) w5[tid-9]  = wk5[c*25 + tid-9];
  else if (tid < 83) w7[tid-34] = wk7[c*49 + tid-34];
  const unsigned short* ip = in + (size_t)(b*256 + c) * 4096;
  for (int idx = tid; idx < TW*TW; idx += 256) {
    const int ty = idx / TW, tx = idx - ty*TW;
    const int gy = ty - 3, gx = tx - 3;
    A[idx] = (gy >= 0 && gy < 64 && gx >= 0 && gx < 64) ? bf2f(ip[gy*64 + gx]) : 0.0f;
  }
  __syncthreads();
  const float* g0 = gates + (size_t)(b*4 + 0) * 4096;
  const float* g1 = gates + (size_t)(b*4 + 1) * 4096;
  const float* g2 = gates + (size_t)(b*4 + 2) * 4096;
  const float* g3 = gates + (size_t)(b*4 + 3) * 4096;
  float v[16], acc[16];
  #pragma unroll
  for (int ii = 0; ii < 16; ++ii) {
    const int pix = ii*256 + tid;
    const int y = pix >> 6, x = pix & 63;
    float s = 0.f;
    #pragma unroll
    for (int ky = 0; ky < 3; ++ky)
      #pragma unroll
      for (int kx = 0; kx < 3; ++kx)
        s += w3[ky*3 + kx] * A[(y+2+ky)*TW + (x+2+kx)];
    v[ii] = gelu_f(s);
    acc[ii] = v[ii] * g0[pix];
  }
  __syncthreads();
  #pragma unroll
  for (int ii = 0; ii < 16; ++ii) {
    const int pix = ii*256 + tid;
    A[((pix >> 6) + 3)*TW + (pix & 63) + 3] = v[ii];
  }
  __syncthreads();
  #pragma unroll
  for (int ii = 0; ii < 16; ++ii) {
    const int pix = ii*256 + tid;
    const int y = pix >> 6, x = pix & 63;
    float s = 0.f;
    #pragma unroll
    for (int ky = 0; ky < 5; ++ky)
      #pragma unroll
      for (int kx = 0; kx < 5; ++kx)
        s += w5[ky*5 + kx] * A[(y+1+ky)*TW + (x+1+kx)];
    v[ii] = gelu_f(s);
    acc[ii] += v[ii] * g1[pix];
  }
  __syncthreads();
  #pragma unroll
  for (int ii = 0; ii < 16; ++ii) {
    const int pix = ii*256 + tid;
    A[((pix >> 6) + 3)*TW + (pix & 63) + 3] = v[ii];
  }
  __syncthreads();
  float msum = 0.f;
  #pragma unroll
  for (int ii = 0; ii < 16; ++ii) {
    const int pix = ii*256 + tid;
    const int y = pix >> 6, x = pix & 63;
    float s = 0.f;
    #pragma unroll
    for (int ky = 0; ky < 7; ++ky)
      #pragma unroll
      for (int kx = 0; kx < 7; ++kx)
        s += w7[ky*7 + kx] * A[(y+ky)*TW + (x+kx)];
    v[ii] = gelu_f(s);
    acc[ii] += v[ii] * g2[pix];
    msum += v[ii];
  }
  #pragma unroll
  for (int off = 32; off >= 1; off >>= 1) msum += __shfl_xor(msum, off, 64);
  if ((tid & 63) == 0) red[tid >> 6] = msum;
  __syncthreads();
  const float vg = gelu_f((red[0]+red[1]+red[2]+red[3]) * (1.0f/4096.0f));
  unsigned short* vp = out + (size_t)(b*256 + c) * 4096;
  #pragma unroll
  for (int ii = 0; ii < 16; ++ii) {
    const int pix = ii*256 + tid;
    vp[pix] = f2bf(acc[ii] + vg * g3[pix]);
  }
}

// ---------------------------------------------------------------------------
// MFMA h-GEMM: v_mod[b,d,hw] = sum_c h_w[d,c]*vall[b,c,hw] + h_b[d].
// Output: vlin[b][m=d*16+(hw>>8)][dim=hw&255] bf16 via LDS-staged 128B-dense
// row writes (replaces round-7's 2B scatter). grid (64 hw, 4 d, 8 b).
// ---------------------------------------------------------------------------
__global__ __launch_bounds__(256) void mfma_h(
    const unsigned short* __restrict__ vall, const unsigned short* __restrict__ hwb,
    const float* __restrict__ hb, unsigned short* __restrict__ vlin) {
  __shared__ unsigned short Bs[64][264];
  __shared__ unsigned short Ts[64][72];   // [d_local][dim_local], 144B rows (16B mult)
  const int hw0 = blockIdx.x * 64, d0 = blockIdx.y * 64, b = blockIdx.z;
  const int tid = threadIdx.x, w = tid >> 6, l = tid & 63;
  const int lr = l & 15, lk = l >> 4;
  const int cl = tid >> 3, hl = (tid & 7) * 8;
  #pragma unroll
  for (int c0 = 0; c0 < 256; c0 += 32) {
    const unsigned short* sp = vall + (size_t)(b*256 + c0 + cl)*4096 + hw0 + hl;
    ushort4 u0 = *(const ushort4*)sp;
    ushort4 u1 = *(const ushort4*)(sp + 4);
    Bs[hl+0][c0+cl] = u0.x; Bs[hl+1][c0+cl] = u0.y;
    Bs[hl+2][c0+cl] = u0.z; Bs[hl+3][c0+cl] = u0.w;
    Bs[hl+4][c0+cl] = u1.x; Bs[hl+5][c0+cl] = u1.y;
    Bs[hl+6][c0+cl] = u1.z; Bs[hl+7][c0+cl] = u1.w;
  }
  __syncthreads();
  const int dw = d0 + w*16;
  const unsigned short* ap = hwb + (size_t)(dw + lr)*256 + lk*8;
  f32x4 acc[4] = {{0.f,0.f,0.f,0.f},{0.f,0.f,0.f,0.f},{0.f,0.f,0.f,0.f},{0.f,0.f,0.f,0.f}};
  #pragma unroll
  for (int k0 = 0; k0 < 256; k0 += 32) {
    bf16x8 a = *reinterpret_cast<const bf16x8*>(ap + k0);
    #pragma unroll
    for (int j = 0; j < 4; ++j) {
      bf16x8 bv = *reinterpret_cast<const bf16x8*>(&Bs[j*16 + lr][k0 + lk*8]);
      acc[j] = __builtin_amdgcn_mfma_f32_16x16x32_bf16(a, bv, acc[j], 0, 0, 0);
    }
  }
  float hbv[4];
  #pragma unroll
  for (int rr = 0; rr < 4; ++rr) hbv[rr] = hb[dw + lk*4 + rr];
  #pragma unroll
  for (int j = 0; j < 4; ++j)
    #pragma unroll
    for (int rr = 0; rr < 4; ++rr)
      Ts[w*16 + lk*4 + rr][j*16 + lr] = f2bf(acc[j][rr] + hbv[rr]);
  __syncthreads();
  const int q = hw0 >> 8, dim0 = hw0 & 255;
  #pragma unroll
  for (int it = 0; it < 2; ++it) {
    const int dl = it*32 + (tid >> 3);
    const int ch = tid & 7;
    const int m = (d0 + dl)*16 + q;
    uint4 v = *(const uint4*)&Ts[dl][ch*8];
    *(uint4*)&vlin[((size_t)(b*4096 + m))*256 + dim0 + ch*8] = v;
  }
}

// ---------------------------------------------------------------------------
// bf16 transpose: v_tb[b][dim][m] from vlin[b][m][dim]. 64x64 tiles,
// grid (64 m-tiles, 4 dim-tiles, 8 b) = 2048.
// ---------------------------------------------------------------------------
__global__ __launch_bounds__(256) void trans_bf(
    const unsigned short* __restrict__ vlin, unsigned short* __restrict__ vt) {
  __shared__ unsigned short T[64][72];
  const int tid = threadIdx.x;
  const int m0 = blockIdx.x * 64, d0 = blockIdx.y * 64, b = blockIdx.z;
  #pragma unroll
  for (int it = 0; it < 2; ++it) {
    const int ml = it*32 + (tid >> 3);
    const int ch = tid & 7;
    uint4 v = *(const uint4*)&vlin[((size_t)(b*4096 + m0 + ml))*256 + d0 + ch*8];
    *(uint4*)&T[ml][ch*8] = v;
  }
  __syncthreads();
  #pragma unroll
  for (int it = 0; it < 2; ++it) {
    const int dl = it*32 + (tid >> 3);
    const int ch = tid & 7;
    unsigned short tmp[8];
    #pragma unroll
    for (int k = 0; k < 8; ++k) tmp[k] = T[ch*8 + k][dl];
    *(uint4*)&vt[((size_t)(b*256 + d0 + dl))*4096 + m0 + ch*8] = *(uint4*)tmp;
  }
}

// ---------------------------------------------------------------------------
// FUSED attention + PV with bf16 MFMA. Pass-2 attn stores now staged in a
// per-wave fp32 LDS tile and flushed every 2 m-tiles as 128B-dense rows.
// Block = (bh, 16-row n-tile), 4 waves each own an m-quarter. grid = 1024.
// ---------------------------------------------------------------------------
__global__ __launch_bounds__(256) void attn_pv(
    const unsigned short* __restrict__ qb, const unsigned short* __restrict__ kb,
    const unsigned short* __restrict__ vt, float* __restrict__ attn,
    unsigned short* __restrict__ aout) {
  const int blk = blockIdx.x;
  const int bh = blk & 63, nt = blk >> 6;
  const int b = bh >> 3, h = bh & 7;
  const int tid = threadIdx.x;
  const int w = tid >> 6, l = tid & 63;
  const int lr = l & 15, lk = l >> 4;
  const int n0 = nt * 16;
  __shared__ float rs[4][16];
  __shared__ unsigned short pl[4][16][40];
  __shared__ float ps[4][16][34];
  __shared__ float osum[4][16][32];
  bf16x8 aq = *reinterpret_cast<const bf16x8*>(
      qb + ((size_t)(b*256 + n0 + lr))*256 + h*32 + lk*8);
  const unsigned short* kbase = kb + (size_t)b*4096*256 + h*32 + lk*8;
  // pass 1: row sums
  float sum[4] = {0.f, 0.f, 0.f, 0.f};
  #pragma unroll 2
  for (int mt = 0; mt < 64; ++mt) {
    const int m0 = w*1024 + mt*16;
    bf16x8 bk = *reinterpret_cast<const bf16x8*>(kbase + (size_t)(m0 + lr)*256);
    f32x4 d = __builtin_amdgcn_mfma_f32_16x16x32_bf16(aq, bk, (f32x4){0.f,0.f,0.f,0.f}, 0, 0, 0);
    #pragma unroll
    for (int r = 0; r < 4; ++r) sum[r] += __expf(d[r] * CSCALE);
  }
  #pragma unroll
  for (int r = 0; r < 4; ++r) {
    #pragma unroll
    for (int m = 1; m < 16; m <<= 1) sum[r] += __shfl_xor(sum[r], m, 64);
  }
  if (lr == 0) {
    #pragma unroll
    for (int r = 0; r < 4; ++r) rs[w][lk*4 + r] = sum[r];
  }
  __syncthreads();
  float invS[4];
  #pragma unroll
  for (int r = 0; r < 4; ++r) {
    const int rowi = lk*4 + r;
    invS[r] = 1.0f / (rs[0][rowi] + rs[1][rowi] + rs[2][rowi] + rs[3][rowi]);
  }
  // pass 2: staged attn store + PV
  float* ab = attn + ((size_t)bh*256 + n0) * 4096;
  const unsigned short* vb = vt + ((size_t)(b*256 + h*32))*4096;
  const int fr = l >> 5;          // flush: row parity lane group
  const int fm = l & 31;          // flush: m within 32-chunk
  f32x4 acc0 = {0.f,0.f,0.f,0.f}, acc1 = {0.f,0.f,0.f,0.f};
  for (int mt = 0; mt < 64; ++mt) {
    const int m0 = w*1024 + mt*16;
    bf16x8 bk = *reinterpret_cast<const bf16x8*>(kbase + (size_t)(m0 + lr)*256);
    f32x4 d = __builtin_amdgcn_mfma_f32_16x16x32_bf16(aq, bk, (f32x4){0.f,0.f,0.f,0.f}, 0, 0, 0);
    const int mo = (mt & 1) << 4;
    #pragma unroll
    for (int r = 0; r < 4; ++r) {
      const float p = __expf(d[r] * CSCALE) * invS[r];
      ps[w][lk*4 + r][mo + lr] = p;
      pl[w][lk*4 + r][mo + lr] = f2bf(p);
    }
    if (mt & 1) {
      const int mb = w*1024 + (mt - 1)*16;
      bf16x8 pa = *reinterpret_cast<const bf16x8*>(&pl[w][lr][lk*8]);
      bf16x8 bv0 = *reinterpret_cast<const bf16x8*>(vb + (size_t)lr*4096 + mb + lk*8);
      bf16x8 bv1 = *reinterpret_cast<const bf16x8*>(vb + (size_t)(16 + lr)*4096 + mb + lk*8);
      acc0 = __builtin_amdgcn_mfma_f32_16x16x32_bf16(pa, bv0, acc0, 0, 0, 0);
      acc1 = __builtin_amdgcn_mfma_f32_16x16x32_bf16(pa, bv1, acc1, 0, 0, 0);
      // flush 16 rows x 32 m of fp32 p: 128B-dense per 2-row store inst
      #pragma unroll
      for (int i = 0; i < 8; ++i) {
        const int row = i*2 + fr;
        ab[(size_t)row*4096 + mb + fm] = ps[w][row][fm];
      }
    }
  }
  #pragma unroll
  for (int r = 0; r < 4; ++r) {
    osum[w][lk*4 + r][lr]      = acc0[r];
    osum[w][lk*4 + r][16 + lr] = acc1[r];
  }
  __syncthreads();
  for (int i = tid; i < 512; i += 256) {
    const int n = i >> 5, d = i & 31;
    const float s = osum[0][n][d] + osum[1][n][d] + osum[2][n][d] + osum[3][n][d];
    aout[((size_t)(b*256 + n0 + n))*256 + h*32 + d] = f2bf(s);
  }
}

// ---------------------------------------------------------------------------
// MFMA proj: out0[r][n] = aout[r][:] . proj_w[n][:] + proj_b[n]  (fp32 out)
// ---------------------------------------------------------------------------
__global__ __launch_bounds__(256) void mfma_proj(
    const unsigned short* __restrict__ A, const unsigned short* __restrict__ W,
    const float* __restrict__ pb, float* __restrict__ out) {
  const int r0 = blockIdx.x * 64, n0 = blockIdx.y * 64;
  const int tid = threadIdx.x, w = tid >> 6, l = tid & 63;
  const int lr = l & 15, lk = l >> 4;
  const int rw = r0 + w*16;
  const unsigned short* ap = A + (size_t)(rw + lr)*256 + lk*8;
  f32x4 acc[4] = {{0.f,0.f,0.f,0.f},{0.f,0.f,0.f,0.f},{0.f,0.f,0.f,0.f},{0.f,0.f,0.f,0.f}};
  #pragma unroll
  for (int k0 = 0; k0 < 256; k0 += 32) {
    bf16x8 a = *reinterpret_cast<const bf16x8*>(ap + k0);
    #pragma unroll
    for (int j = 0; j < 4; ++j) {
      bf16x8 b = *reinterpret_cast<const bf16x8*>(W + (size_t)(n0 + j*16 + lr)*256 + k0 + lk*8);
      acc[j] = __builtin_amdgcn_mfma_f32_16x16x32_bf16(a, b, acc[j], 0, 0, 0);
    }
  }
  #pragma unroll
  for (int j = 0; j < 4; ++j) {
    const int n = n0 + j*16 + lr;
    const float bb = pb[n];
    #pragma unroll
    for (int rr = 0; rr < 4; ++rr)
      out[(size_t)(rw + lk*4 + rr)*256 + n] = acc[j][rr] + bb;
  }
}

} // namespace

extern "C" void kernel_launch(void* const* d_in, const int* in_sizes, int n_in,
                              void* d_out, int out_size, void* d_ws, size_t ws_size,
                              hipStream_t stream) {
  (void)in_sizes; (void)n_in; (void)out_size; (void)ws_size;
  const float* latents = (const float*)d_in[0];
  const float* context = (const float*)d_in[1];
  const float* q_w    = (const float*)d_in[2];
  const float* k_w    = (const float*)d_in[3];
  const float* f_w    = (const float*)d_in[4];
  const float* f_b    = (const float*)d_in[5];
  const float* h_w    = (const float*)d_in[6];
  const float* h_b    = (const float*)d_in[7];
  const float* fk0    = (const float*)d_in[8];
  const float* fk1    = (const float*)d_in[9];
  const float* fk2    = (const float*)d_in[10];
  const float* proj_w = (const float*)d_in[11];
  const float* proj_b = (const float*)d_in[12];

  float* out0 = (float*)d_out;                  // (8,256,256)
  float* attn = out0 + (size_t)8*256*256;       // (8,8,256,4096)

  // workspace layout (byte offsets), total ~90 MB
  char* w = (char*)d_ws;
  unsigned short* ctx_bf = (unsigned short*)(w + 0x0);        // 16 MB (8,4096,256)
  unsigned short* vcv    = (unsigned short*)(w + 0x1000000);  // 16 MB vctx/vall (in-place conv)
  unsigned short* k_bf   = (unsigned short*)(w + 0x2100000);  // 16 MB (8,4096,256)
  unsigned short* v_tb   = (unsigned short*)(w + 0x3100000);  // 16 MB (8,256,4096) vT[dim][m]
  unsigned short* q_bf   = (unsigned short*)(w + 0x4100000);  //  1 MB (8,256,256)
  unsigned short* lat_bf = (unsigned short*)(w + 0x4200000);  //  1 MB
  unsigned short* qw_bf  = (unsigned short*)(w + 0x4300000);  // 128 KB
  unsigned short* kw_bf  = (unsigned short*)(w + 0x4340000);  // 128 KB
  unsigned short* fw_bf  = (unsigned short*)(w + 0x4380000);  // 130 KB
  unsigned short* hw_bf  = (unsigned short*)(w + 0x43C0000);  // 128 KB
  unsigned short* pw_bf  = (unsigned short*)(w + 0x4400000);  // 128 KB
  float*          gates  = (float*)(w + 0x4440000);           // 512 KB fp32
  unsigned short* aout_bf= (unsigned short*)(w + 0x44C0000);  //  1 MB
  unsigned short* vlin_bf= (unsigned short*)(w + 0x4600000);  // 16 MB (8,4096,256) [m][dim]

  cast_all<<<2257, 256, 0, stream>>>(context, latents, q_w, k_w, f_w, h_w, proj_w,
                                     ctx_bf, lat_bf, qw_bf, kw_bf, fw_bf, hw_bf, pw_bf);
  mfma_qk  <<<dim3(32, 4),  256, 0, stream>>>(lat_bf, qw_bf, q_bf);
  mfma_fk  <<<dim3(512, 9), 256, 0, stream>>>(ctx_bf, kw_bf, fw_bf, f_b, k_bf, vcv, gates);
  fused_conv<<<2048, 256, 0, stream>>>(vcv, fk0, fk1, fk2, gates, vcv);
  mfma_h   <<<dim3(64, 4, 8), 256, 0, stream>>>(vcv, hw_bf, h_b, vlin_bf);
  trans_bf <<<dim3(64, 4, 8), 256, 0, stream>>>(vlin_bf, v_tb);
  attn_pv  <<<1024, 256, 0, stream>>>(q_bf, k_bf, v_tb, attn, aout_bf);
  mfma_proj<<<dim3(32, 4), 256, 0, stream>>>(aout_bf, pw_bf, proj_b, out0);
}